// Round 1
// baseline (578.242 us; speedup 1.0000x reference)
//
#include <hip/hip_runtime.h>

#define DIMC 384
#define NTOK 1024
#define BATCH 32
#define KT12 12

using short8 = __attribute__((ext_vector_type(8))) short;
using f32x4  = __attribute__((ext_vector_type(4))) float;
using uint4_ = __attribute__((ext_vector_type(4))) unsigned int;
typedef unsigned short u16;

#define MFMA16 __builtin_amdgcn_mfma_f32_16x16x32_bf16

__device__ __forceinline__ u16 f2bf(float f) {
    unsigned int u = __builtin_bit_cast(unsigned int, f);
    u += 0x7FFFu + ((u >> 16) & 1u);
    return (u16)(u >> 16);
}
__device__ __forceinline__ float bf2f(u16 h) {
    unsigned int u = ((unsigned int)h) << 16;
    return __builtin_bit_cast(float, u);
}

// Unified fragment-contiguous swizzle for matrix M[R][K] (K = contraction):
//   flat = ((r>>4)*KT + (k>>5))*512 + (((k>>3)&3)*16 + (r&15))*8 + (k&7)
// One MFMA A/B fragment (rt, kt) = 1 KB contiguous at ((rt*KT+kt)*64+lane)*8.

// ---------------------------------------------------------------------------
// transpose_sw: X (b, c, n) fp32 -> X_sw (b, swizzle R=n K=c) bf16.
// grid (16, 6, BATCH), 256 threads.
// ---------------------------------------------------------------------------
__global__ __launch_bounds__(256) void transpose_sw(
    const float* __restrict__ X, u16* __restrict__ Xsw)
{
    __shared__ float tl[64 * 65];
    const int b = blockIdx.z, n0 = blockIdx.x * 64, c0 = blockIdx.y * 64;
    const int t = threadIdx.x;

#pragma unroll
    for (int p = 0; p < 4; ++p) {
        int idx = p * 256 + t;
        int c = idx >> 4, n4 = (idx & 15) * 4;
        f32x4 v = *(const f32x4*)(X + ((size_t)b * DIMC + c0 + c) * NTOK + n0 + n4);
#pragma unroll
        for (int i = 0; i < 4; ++i) tl[c * 65 + n4 + i] = v[i];
    }
    __syncthreads();
    u16* dstb = Xsw + (size_t)b * NTOK * DIMC;
#pragma unroll
    for (int p = 0; p < 2; ++p) {
        int g = p * 256 + t;  // [3:0]=n15 [5:4]=quad [6]=ktl [8:7]=rg
        int n15 = g & 15, quad = (g >> 4) & 3, ktl = (g >> 6) & 1, rg = g >> 7;
        int c8 = ktl * 32 + quad * 8;
        int nl = rg * 16 + n15;
        uint4_ pk;
#pragma unroll
        for (int i = 0; i < 4; ++i) {
            u16 lo = f2bf(tl[(c8 + 2 * i) * 65 + nl]);
            u16 hi = f2bf(tl[(c8 + 2 * i + 1) * 65 + nl]);
            pk[i] = (unsigned)lo | ((unsigned)hi << 16);
        }
        size_t dst = (((size_t)(n0 >> 4) + rg) * KT12 + (c0 >> 5) + ktl) * 512 + (size_t)(g & 63) * 8;
        *(uint4_*)(dstb + dst) = pk;
    }
}

// ---------------------------------------------------------------------------
// wcvt_sw: 4 weight matrices (384x384 fp32 [d][c]) -> swizzle bf16 (R=d, K=c),
// concatenated. Matrix 0 (Wq) pre-scaled by scale*log2e. grid (72,4), 256 thr.
// ---------------------------------------------------------------------------
__global__ __launch_bounds__(256) void wcvt_sw(
    const float* __restrict__ w0, const float* __restrict__ w1,
    const float* __restrict__ w2, const float* __restrict__ w3,
    u16* __restrict__ dst, float s0)
{
    const float* srcs[4] = {w0, w1, w2, w3};
    const float* s = srcs[blockIdx.y];
    float scl = (blockIdx.y == 0) ? s0 : 1.0f;
    u16* d = dst + (size_t)blockIdx.y * DIMC * DIMC;
    int e0 = (blockIdx.x * 256 + threadIdx.x) * 8;
    int dd = e0 / DIMC, c8 = e0 % DIMC;
    f32x4 a = *(const f32x4*)(s + e0);
    f32x4 b2 = *(const f32x4*)(s + e0 + 4);
    uint4_ pk;
    pk[0] = (unsigned)f2bf(a[0] * scl) | ((unsigned)f2bf(a[1] * scl) << 16);
    pk[1] = (unsigned)f2bf(a[2] * scl) | ((unsigned)f2bf(a[3] * scl) << 16);
    pk[2] = (unsigned)f2bf(b2[0] * scl) | ((unsigned)f2bf(b2[1] * scl) << 16);
    pk[3] = (unsigned)f2bf(b2[2] * scl) | ((unsigned)f2bf(b2[3] * scl) << 16);
    size_t off = ((size_t)(dd >> 4) * KT12 + (c8 >> 5)) * 512 +
                 (size_t)((((c8 >> 3) & 3) * 16 + (dd & 15)) * 8);
    *(uint4_*)(d + off) = pk;
}

// ---------------------------------------------------------------------------
// proj3_sw: q/k/v projections in one launch. D[row][col] = sum_k A[r][k]*B[c][k]
// + bias, out bf16 swizzled. 128x64 tile, 4 waves x 2 row-strips (B frags
// amortized over 2 MFMAs). grid (48, 3, BATCH), 256 threads.
//   s=0: A=rgb_sw B=Wq  -> q_sw (ktd=12, bias cols, x scale)
//   s=1: A=ms_sw  B=Wk  -> k_sw (ktd=12, bias cols)
//   s=2: A=Wv     B=ms_sw -> v_sw (ktd=32, bias rows)
// ---------------------------------------------------------------------------
__global__ __launch_bounds__(256) void proj3_sw(
    const u16* __restrict__ rgb_sw, const u16* __restrict__ ms_sw,
    const u16* __restrict__ w_sw,
    u16* __restrict__ q_sw, u16* __restrict__ k_sw, u16* __restrict__ v_sw,
    const float* __restrict__ bq, const float* __restrict__ bk,
    const float* __restrict__ bv, float s0)
{
    __shared__ __align__(16) u16 t16[128 * 76];
    const int s = blockIdx.y, b = blockIdx.z, tile = blockIdx.x;
    const size_t TB = (size_t)NTOK * DIMC, WN = (size_t)DIMC * DIMC;
    const u16 *A, *B; u16* O; const float* bias;
    int ktd, bRow, r0, c0; float bsc = 1.f;
    if (s == 0) {
        A = rgb_sw + b * TB; B = w_sw; O = q_sw + b * TB; bias = bq;
        ktd = 12; bRow = 0; r0 = (tile / 6) * 128; c0 = (tile % 6) * 64; bsc = s0;
    } else if (s == 1) {
        A = ms_sw + b * TB; B = w_sw + WN; O = k_sw + b * TB; bias = bk;
        ktd = 12; bRow = 0; r0 = (tile / 6) * 128; c0 = (tile % 6) * 64;
    } else {
        A = w_sw + 2 * WN; B = ms_sw + b * TB; O = v_sw + b * TB; bias = bv;
        ktd = 32; bRow = 1; r0 = (tile / 16) * 128; c0 = (tile % 16) * 64;
    }

    const int t = threadIdx.x, w = t >> 6, lane = t & 63;
    const int l15 = lane & 15, quad = lane >> 4;

    f32x4 acc[2][4];
#pragma unroll
    for (int ss = 0; ss < 2; ++ss)
#pragma unroll
        for (int mc = 0; mc < 4; ++mc) acc[ss][mc] = (f32x4){0.f, 0.f, 0.f, 0.f};

    const u16* aP = A + ((size_t)(r0 >> 4) + w * 2) * (KT12 * 512) + (size_t)lane * 8;
    const u16* bP = B + (size_t)(c0 >> 4) * (KT12 * 512) + (size_t)lane * 8;
#pragma unroll
    for (int dk = 0; dk < 12; ++dk) {
        short8 a0 = *(const short8*)(aP + dk * 512);
        short8 a1 = *(const short8*)(aP + (KT12 + dk) * 512);
#pragma unroll
        for (int mc = 0; mc < 4; ++mc) {
            short8 bf = *(const short8*)(bP + ((size_t)mc * KT12 + dk) * 512);
            acc[0][mc] = MFMA16(a0, bf, acc[0][mc], 0, 0, 0);
            acc[1][mc] = MFMA16(a1, bf, acc[1][mc], 0, 0, 0);
        }
    }

    if (bRow) {
#pragma unroll
        for (int ss = 0; ss < 2; ++ss) {
            f32x4 bv4 = *(const f32x4*)(bias + r0 + w * 32 + ss * 16 + quad * 4);
#pragma unroll
            for (int mc = 0; mc < 4; ++mc)
#pragma unroll
                for (int r = 0; r < 4; ++r) acc[ss][mc][r] += bv4[r];
        }
    } else {
#pragma unroll
        for (int mc = 0; mc < 4; ++mc) {
            float bc = bias[c0 + mc * 16 + l15] * bsc;
#pragma unroll
            for (int ss = 0; ss < 2; ++ss)
#pragma unroll
                for (int r = 0; r < 4; ++r) acc[ss][mc][r] += bc;
        }
    }

#pragma unroll
    for (int ss = 0; ss < 2; ++ss)
#pragma unroll
        for (int mc = 0; mc < 4; ++mc)
#pragma unroll
            for (int r = 0; r < 4; ++r)
                t16[(w * 32 + ss * 16 + quad * 4 + r) * 76 + mc * 16 + l15] = f2bf(acc[ss][mc][r]);
    __syncthreads();
#pragma unroll
    for (int p = 0; p < 4; ++p) {
        int g = p * 256 + t;  // [5:0]=lane' [6]=ktl [9:7]=rg
        int lan = g & 63, ktl = (g >> 6) & 1, rg = g >> 7;
        int row = rg * 16 + (lan & 15);
        int col = ktl * 32 + ((lan >> 4) & 3) * 8;
        uint4_ v = *(const uint4_*)(t16 + row * 76 + col);
        size_t dst = (((size_t)(r0 >> 4) + rg) * ktd + (c0 >> 5) + ktl) * 512 + (size_t)lan * 8;
        *(uint4_*)(O + dst) = v;
    }
}

// ---------------------------------------------------------------------------
// projf_sw: final projection. out[b][d][n] = sum_c Wf[d][c]*O[n][c] + bf.
// A=Wf (swizzle), B=o_sw (swizzle). 128x64 tile, fp32 row-major out.
// grid (48, BATCH), 256 threads.
// ---------------------------------------------------------------------------
__global__ __launch_bounds__(256) void projf_sw(
    const u16* __restrict__ wf_sw, const u16* __restrict__ osw,
    const float* __restrict__ bfp, float* __restrict__ out)
{
    __shared__ __align__(16) float t32[128 * 68];
    const int b = blockIdx.y, tile = blockIdx.x;
    const int r0 = (tile / 16) * 128, c0 = (tile % 16) * 64;
    const size_t TB = (size_t)NTOK * DIMC;

    const int t = threadIdx.x, w = t >> 6, lane = t & 63;
    const int quad = lane >> 4;

    f32x4 acc[2][4];
#pragma unroll
    for (int ss = 0; ss < 2; ++ss)
#pragma unroll
        for (int mc = 0; mc < 4; ++mc) acc[ss][mc] = (f32x4){0.f, 0.f, 0.f, 0.f};

    const u16* aP = wf_sw + ((size_t)(r0 >> 4) + w * 2) * (KT12 * 512) + (size_t)lane * 8;
    const u16* bP = osw + (size_t)b * TB + (size_t)(c0 >> 4) * (KT12 * 512) + (size_t)lane * 8;
#pragma unroll
    for (int dk = 0; dk < 12; ++dk) {
        short8 a0 = *(const short8*)(aP + dk * 512);
        short8 a1 = *(const short8*)(aP + (KT12 + dk) * 512);
#pragma unroll
        for (int mc = 0; mc < 4; ++mc) {
            short8 bf = *(const short8*)(bP + ((size_t)mc * KT12 + dk) * 512);
            acc[0][mc] = MFMA16(a0, bf, acc[0][mc], 0, 0, 0);
            acc[1][mc] = MFMA16(a1, bf, acc[1][mc], 0, 0, 0);
        }
    }
#pragma unroll
    for (int ss = 0; ss < 2; ++ss) {
        f32x4 bv4 = *(const f32x4*)(bfp + r0 + w * 32 + ss * 16 + quad * 4);
#pragma unroll
        for (int mc = 0; mc < 4; ++mc)
#pragma unroll
            for (int r = 0; r < 4; ++r) acc[ss][mc][r] += bv4[r];
    }

#pragma unroll
    for (int ss = 0; ss < 2; ++ss)
#pragma unroll
        for (int mc = 0; mc < 4; ++mc)
#pragma unroll
            for (int r = 0; r < 4; ++r)
                t32[(w * 32 + ss * 16 + quad * 4 + r) * 68 + mc * 16 + (lane & 15)] = acc[ss][mc][r];
    __syncthreads();
    float* Ob = out + (size_t)b * DIMC * NTOK;
#pragma unroll
    for (int p = 0; p < 8; ++p) {
        int g = p * 256 + t;
        int row = g >> 4, c4 = (g & 15) * 4;
        f32x4 v = *(const f32x4*)(t32 + row * 68 + c4);
        *(f32x4*)(Ob + (size_t)(r0 + row) * NTOK + c0 + c4) = v;
    }
}

// ---------------------------------------------------------------------------
// attn_wave: flash attention with a barrier-free main loop.
// 4 waves/block = 2 q-subtiles x 2 KV-halves; each wave independently owns
// 16 q rows over 512 keys (8 tiles of 64). K and V fragments are streamed
// directly from global (1 KB coalesced per fragment); per-XCD batch mapping
// (b = (bid&7) + 8*((bid>>3)&3)) keeps each batch's 1.5 MB K+V stream
// resident in one XCD L2. Softmax P transpose goes through a tiny per-wave
// LDS buffer (wave-internal, no barriers). Pairwise (m,l,O) merge of the
// two KV halves happens in an epilogue-only barrier region.
// Occupancy: 4096 waves total, LDS 18.7 KB, __launch_bounds__(256,3)
// -> 12 waves/CU (vs 8 in the staged version). grid (1024), 256 threads.
// ---------------------------------------------------------------------------
__global__ __launch_bounds__(256, 3) void attn_wave(
    const u16* __restrict__ qsw, const u16* __restrict__ ksw,
    const u16* __restrict__ vsw, u16* __restrict__ osw)
{
    __shared__ __align__(16) float mbuf[2][16][68];   // per-pair merge chunk
    __shared__ float mlbuf[2][16][2];                 // per-pair (m, l)
    __shared__ __align__(16) u16 plds[4][1216];       // per-wave 16x76 P buf

    const int bid = blockIdx.x;
    const int b = (bid & 7) + 8 * ((bid >> 3) & 3);   // 4 batches per XCD
    const int qb32 = bid >> 5;                        // 32-q block index
    const int t = threadIdx.x, w = t >> 6, lane = t & 63;
    const int l15 = lane & 15, quad = lane >> 4;
    const int pairid = w >> 1, kvh = w & 1;
    const int rt = qb32 * 2 + pairid;                 // 16-q frag row-tile

    const size_t TB = (size_t)NTOK * DIMC;
    const u16* kb = ksw + (size_t)b * TB;
    const u16* vb = vsw + (size_t)b * TB;
    u16* pw = &plds[w][0];

    // Q fragments resident (q pre-scaled by scale*log2e at projection)
    short8 qf[12];
    const u16* qp = qsw + (size_t)b * TB + (size_t)rt * (KT12 * 512) + (size_t)lane * 8;
#pragma unroll
    for (int dk = 0; dk < 12; ++dk) qf[dk] = *(const short8*)(qp + dk * 512);

    f32x4 Oa[24];
#pragma unroll
    for (int i = 0; i < 24; ++i) Oa[i] = (f32x4){0.f, 0.f, 0.f, 0.f};
    float m_run[4], l_run[4];
#pragma unroll
    for (int r = 0; r < 4; ++r) { m_run[r] = -1e30f; l_run[r] = 0.f; }

    for (int it = 0; it < 8; ++it) {
        const int mt = kvh * 8 + it;

        // ---- QK: S[16 q][64 keys], K frags direct from global (L2) ----
        f32x4 s[4];
#pragma unroll
        for (int i = 0; i < 4; ++i) s[i] = (f32x4){0.f, 0.f, 0.f, 0.f};
        const u16* kt0 = kb + (size_t)(4 * mt) * (KT12 * 512) + (size_t)lane * 8;
        __builtin_amdgcn_s_setprio(1);
#pragma unroll
        for (int dk = 0; dk < 12; ++dk) {
#pragma unroll
            for (int mc = 0; mc < 4; ++mc) {
                short8 kf = *(const short8*)(kt0 + ((size_t)mc * KT12 + dk) * 512);
                s[mc] = MFMA16(qf[dk], kf, s[mc], 0, 0, 0);
            }
        }
        __builtin_amdgcn_s_setprio(0);

        // ---- online softmax (log2-domain, deferred-max THR=8) ----
        float mx4[4];
#pragma unroll
        for (int r = 0; r < 4; ++r) {
            float mx = fmaxf(fmaxf(s[0][r], s[1][r]), fmaxf(s[2][r], s[3][r]));
            mx = fmaxf(mx, __shfl_xor(mx, 1));
            mx = fmaxf(mx, __shfl_xor(mx, 2));
            mx = fmaxf(mx, __shfl_xor(mx, 4));
            mx = fmaxf(mx, __shfl_xor(mx, 8));
            mx4[r] = mx;
        }
        int grow = (mx4[0] > m_run[0] + 8.f) | (mx4[1] > m_run[1] + 8.f) |
                   (mx4[2] > m_run[2] + 8.f) | (mx4[3] > m_run[3] + 8.f);
        if (__any(grow)) {
            float alpha[4];
#pragma unroll
            for (int r = 0; r < 4; ++r) {
                float mn = fmaxf(m_run[r], mx4[r]);
                alpha[r] = exp2f(m_run[r] - mn);
                m_run[r] = mn;
                l_run[r] *= alpha[r];
            }
#pragma unroll
            for (int ci = 0; ci < 24; ++ci)
#pragma unroll
                for (int r = 0; r < 4; ++r) Oa[ci][r] *= alpha[r];
        }
#pragma unroll
        for (int r = 0; r < 4; ++r) {
            float ls = 0.f;
#pragma unroll
            for (int mc = 0; mc < 4; ++mc) {
                float p = exp2f(s[mc][r] - m_run[r]);
                u16 pb = f2bf(p);
                pw[(quad * 4 + r) * 76 + mc * 16 + l15] = pb;
                ls += bf2f(pb);  // denominator from rounded P -> exact normalization
            }
            ls += __shfl_xor(ls, 1);
            ls += __shfl_xor(ls, 2);
            ls += __shfl_xor(ls, 4);
            ls += __shfl_xor(ls, 8);
            l_run[r] += ls;
        }

        // ---- PV: P from per-wave LDS (wave-internal), V direct global ----
        short8 pa0 = *(const short8*)(pw + l15 * 76 + quad * 8);
        short8 pa1 = *(const short8*)(pw + l15 * 76 + 32 + quad * 8);
        const u16* vp = vb + ((size_t)(mt * 2) * 64 + lane) * 8;
        __builtin_amdgcn_s_setprio(1);
#pragma unroll
        for (int ci = 0; ci < 24; ++ci) {
            short8 v0 = *(const short8*)(vp + ((size_t)ci * 32) * 512);
            short8 v1 = *(const short8*)(vp + ((size_t)ci * 32 + 1) * 512);
            Oa[ci] = MFMA16(pa0, v0, Oa[ci], 0, 0, 0);
            Oa[ci] = MFMA16(pa1, v1, Oa[ci], 0, 0, 0);
        }
        __builtin_amdgcn_s_setprio(0);
    }

    // ---- epilogue: pairwise KV-half merge + normalize + swizzled store ----
    if (kvh == 1 && l15 == 0) {
#pragma unroll
        for (int r = 0; r < 4; ++r) {
            mlbuf[pairid][quad * 4 + r][0] = m_run[r];
            mlbuf[pairid][quad * 4 + r][1] = l_run[r];
        }
    }
    __syncthreads();
    float al0[4], al1[4], rl[4];
    if (kvh == 0) {
#pragma unroll
        for (int r = 0; r < 4; ++r) {
            float m2 = mlbuf[pairid][quad * 4 + r][0];
            float l2 = mlbuf[pairid][quad * 4 + r][1];
            float mm = fmaxf(m_run[r], m2);
            al0[r] = exp2f(m_run[r] - mm);
            al1[r] = exp2f(m2 - mm);
            rl[r] = 1.f / (l_run[r] * al0[r] + l2 * al1[r]);
        }
    }
    u16* od = osw + (size_t)b * TB;
#pragma unroll
    for (int ch = 0; ch < 6; ++ch) {
        if (kvh == 1) {
#pragma unroll
            for (int cc = 0; cc < 4; ++cc)
#pragma unroll
                for (int r = 0; r < 4; ++r)
                    mbuf[pairid][quad * 4 + r][cc * 16 + l15] = Oa[ch * 4 + cc][r];
        }
        __syncthreads();
        if (kvh == 0) {
#pragma unroll
            for (int cc = 0; cc < 4; ++cc)
#pragma unroll
                for (int r = 0; r < 4; ++r) {
                    float mg = Oa[ch * 4 + cc][r] * al0[r] +
                               mbuf[pairid][quad * 4 + r][cc * 16 + l15] * al1[r];
                    pw[(quad * 4 + r) * 76 + cc * 16 + l15] = f2bf(mg * rl[r]);
                }
#pragma unroll
            for (int ktl = 0; ktl < 2; ++ktl) {
                uint4_ vv = *(const uint4_*)(pw + l15 * 76 + ktl * 32 + quad * 8);
                size_t dst = ((size_t)rt * KT12 + ch * 2 + ktl) * 512 + (size_t)lane * 8;
                *(uint4_*)(od + dst) = vv;
            }
        }
        __syncthreads();
    }
}

extern "C" void kernel_launch(void* const* d_in, const int* in_sizes, int n_in,
                              void* d_out, int out_size, void* d_ws, size_t ws_size,
                              hipStream_t stream) {
    const float* rgb = (const float*)d_in[0];
    const float* ms  = (const float*)d_in[1];
    const float* Wq  = (const float*)d_in[2];
    const float* bq  = (const float*)d_in[3];
    const float* Wk  = (const float*)d_in[4];
    const float* bk  = (const float*)d_in[5];
    const float* Wv  = (const float*)d_in[6];
    const float* bv  = (const float*)d_in[7];
    const float* Wf  = (const float*)d_in[8];
    const float* bf_ = (const float*)d_in[9];
    float* outp = (float*)d_out;

    const float SC2 = 0.05103103630798288f * 1.4426950408889634f;  // scale*log2e

    const size_t TN = (size_t)BATCH * NTOK * DIMC;  // 12.58M elems
    const size_t WN = (size_t)DIMC * DIMC;          // 147456
    u16* rgb_sw = (u16*)d_ws;         // swizzle R=n K=c
    u16* ms_sw  = rgb_sw + TN;
    u16* q_sw   = ms_sw + TN;         // R=n K=d (pre-scaled)
    u16* k_sw   = q_sw + TN;          // R=m K=d
    u16* v_sw   = k_sw + TN;          // R=c K=m (KT=32)
    u16* o_sw   = v_sw + TN;          // R=n K=c
    u16* w_sw   = o_sw + TN;          // Wq,Wk,Wv,Wf swizzled concat
    // total ws: 6*25.2MB + 1.2MB = 152 MB

    wcvt_sw<<<dim3(72, 4), 256, 0, stream>>>(Wq, Wk, Wv, Wf, w_sw, SC2);
    transpose_sw<<<dim3(16, 6, BATCH), 256, 0, stream>>>(rgb, rgb_sw);
    transpose_sw<<<dim3(16, 6, BATCH), 256, 0, stream>>>(ms, ms_sw);

    proj3_sw<<<dim3(48, 3, BATCH), 256, 0, stream>>>(
        rgb_sw, ms_sw, w_sw, q_sw, k_sw, v_sw, bq, bk, bv, SC2);

    attn_wave<<<dim3(1024), 256, 0, stream>>>(q_sw, k_sw, v_sw, o_sw);

    projf_sw<<<dim3(48, BATCH), 256, 0, stream>>>(w_sw + 3 * WN, o_sw, bf_, outp);
}

// Round 3
// 344.456 us; speedup vs baseline: 1.6787x; 1.6787x over previous
//
#include <hip/hip_runtime.h>

#define DIMC 384
#define NTOK 1024
#define BATCH 32
#define KT12 12

using short8 = __attribute__((ext_vector_type(8))) short;
using f32x4  = __attribute__((ext_vector_type(4))) float;
using uint4_ = __attribute__((ext_vector_type(4))) unsigned int;
typedef unsigned short u16;

#define MFMA16 __builtin_amdgcn_mfma_f32_16x16x32_bf16

// async global->LDS, 16B/lane. LDS dest = wave-uniform base + lane*16.
#define GLD_LDS16(gp, lp)                                                     \
    __builtin_amdgcn_global_load_lds(                                         \
        (const __attribute__((address_space(1))) void*)(gp),                  \
        (__attribute__((address_space(3))) void*)(lp), 16, 0, 0)

__device__ __forceinline__ u16 f2bf(float f) {
    unsigned int u = __builtin_bit_cast(unsigned int, f);
    u += 0x7FFFu + ((u >> 16) & 1u);
    return (u16)(u >> 16);
}
__device__ __forceinline__ float bf2f(u16 h) {
    unsigned int u = ((unsigned int)h) << 16;
    return __builtin_bit_cast(float, u);
}

// Unified fragment-contiguous swizzle for matrix M[R][K] (K = contraction):
//   flat = ((r>>4)*KT + (k>>5))*512 + (((k>>3)&3)*16 + (r&15))*8 + (k&7)
// One MFMA A/B fragment (rt, kt) = 1 KB contiguous at ((rt*KT+kt)*64+lane)*8.

// ---------------------------------------------------------------------------
// transpose_sw: X (b, c, n) fp32 -> X_sw (b, swizzle R=n K=c) bf16.
// grid (16, 6, BATCH), 256 threads.
// ---------------------------------------------------------------------------
__global__ __launch_bounds__(256) void transpose_sw(
    const float* __restrict__ X, u16* __restrict__ Xsw)
{
    __shared__ float tl[64 * 65];
    const int b = blockIdx.z, n0 = blockIdx.x * 64, c0 = blockIdx.y * 64;
    const int t = threadIdx.x;

#pragma unroll
    for (int p = 0; p < 4; ++p) {
        int idx = p * 256 + t;
        int c = idx >> 4, n4 = (idx & 15) * 4;
        f32x4 v = *(const f32x4*)(X + ((size_t)b * DIMC + c0 + c) * NTOK + n0 + n4);
#pragma unroll
        for (int i = 0; i < 4; ++i) tl[c * 65 + n4 + i] = v[i];
    }
    __syncthreads();
    u16* dstb = Xsw + (size_t)b * NTOK * DIMC;
#pragma unroll
    for (int p = 0; p < 2; ++p) {
        int g = p * 256 + t;  // [3:0]=n15 [5:4]=quad [6]=ktl [8:7]=rg
        int n15 = g & 15, quad = (g >> 4) & 3, ktl = (g >> 6) & 1, rg = g >> 7;
        int c8 = ktl * 32 + quad * 8;
        int nl = rg * 16 + n15;
        uint4_ pk;
#pragma unroll
        for (int i = 0; i < 4; ++i) {
            u16 lo = f2bf(tl[(c8 + 2 * i) * 65 + nl]);
            u16 hi = f2bf(tl[(c8 + 2 * i + 1) * 65 + nl]);
            pk[i] = (unsigned)lo | ((unsigned)hi << 16);
        }
        size_t dst = (((size_t)(n0 >> 4) + rg) * KT12 + (c0 >> 5) + ktl) * 512 + (size_t)(g & 63) * 8;
        *(uint4_*)(dstb + dst) = pk;
    }
}

// ---------------------------------------------------------------------------
// wcvt_sw: 4 weight matrices (384x384 fp32 [d][c]) -> swizzle bf16 (R=d, K=c),
// concatenated. Matrix 0 (Wq) pre-scaled by scale*log2e. grid (72,4), 256 thr.
// ---------------------------------------------------------------------------
__global__ __launch_bounds__(256) void wcvt_sw(
    const float* __restrict__ w0, const float* __restrict__ w1,
    const float* __restrict__ w2, const float* __restrict__ w3,
    u16* __restrict__ dst, float s0)
{
    const float* srcs[4] = {w0, w1, w2, w3};
    const float* s = srcs[blockIdx.y];
    float scl = (blockIdx.y == 0) ? s0 : 1.0f;
    u16* d = dst + (size_t)blockIdx.y * DIMC * DIMC;
    int e0 = (blockIdx.x * 256 + threadIdx.x) * 8;
    int dd = e0 / DIMC, c8 = e0 % DIMC;
    f32x4 a = *(const f32x4*)(s + e0);
    f32x4 b2 = *(const f32x4*)(s + e0 + 4);
    uint4_ pk;
    pk[0] = (unsigned)f2bf(a[0] * scl) | ((unsigned)f2bf(a[1] * scl) << 16);
    pk[1] = (unsigned)f2bf(a[2] * scl) | ((unsigned)f2bf(a[3] * scl) << 16);
    pk[2] = (unsigned)f2bf(b2[0] * scl) | ((unsigned)f2bf(b2[1] * scl) << 16);
    pk[3] = (unsigned)f2bf(b2[2] * scl) | ((unsigned)f2bf(b2[3] * scl) << 16);
    size_t off = ((size_t)(dd >> 4) * KT12 + (c8 >> 5)) * 512 +
                 (size_t)((((c8 >> 3) & 3) * 16 + (dd & 15)) * 8);
    *(uint4_*)(d + off) = pk;
}

// ---------------------------------------------------------------------------
// proj3_sw: q/k/v projections in one launch. D[row][col] = sum_k A[r][k]*B[c][k]
// + bias, out bf16 swizzled. 128x64 tile, 4 waves x 2 row-strips (B frags
// amortized over 2 MFMAs). grid (48, 3, BATCH), 256 threads.
//   s=0: A=rgb_sw B=Wq  -> q_sw (ktd=12, bias cols, x scale)
//   s=1: A=ms_sw  B=Wk  -> k_sw (ktd=12, bias cols)
//   s=2: A=Wv     B=ms_sw -> v_sw (ktd=32, bias rows)
// ---------------------------------------------------------------------------
__global__ __launch_bounds__(256) void proj3_sw(
    const u16* __restrict__ rgb_sw, const u16* __restrict__ ms_sw,
    const u16* __restrict__ w_sw,
    u16* __restrict__ q_sw, u16* __restrict__ k_sw, u16* __restrict__ v_sw,
    const float* __restrict__ bq, const float* __restrict__ bk,
    const float* __restrict__ bv, float s0)
{
    __shared__ __align__(16) u16 t16[128 * 76];
    const int s = blockIdx.y, b = blockIdx.z, tile = blockIdx.x;
    const size_t TB = (size_t)NTOK * DIMC, WN = (size_t)DIMC * DIMC;
    const u16 *A, *B; u16* O; const float* bias;
    int ktd, bRow, r0, c0; float bsc = 1.f;
    if (s == 0) {
        A = rgb_sw + b * TB; B = w_sw; O = q_sw + b * TB; bias = bq;
        ktd = 12; bRow = 0; r0 = (tile / 6) * 128; c0 = (tile % 6) * 64; bsc = s0;
    } else if (s == 1) {
        A = ms_sw + b * TB; B = w_sw + WN; O = k_sw + b * TB; bias = bk;
        ktd = 12; bRow = 0; r0 = (tile / 6) * 128; c0 = (tile % 6) * 64;
    } else {
        A = w_sw + 2 * WN; B = ms_sw + b * TB; O = v_sw + b * TB; bias = bv;
        ktd = 32; bRow = 1; r0 = (tile / 16) * 128; c0 = (tile % 16) * 64;
    }

    const int t = threadIdx.x, w = t >> 6, lane = t & 63;
    const int l15 = lane & 15, quad = lane >> 4;

    f32x4 acc[2][4];
#pragma unroll
    for (int ss = 0; ss < 2; ++ss)
#pragma unroll
        for (int mc = 0; mc < 4; ++mc) acc[ss][mc] = (f32x4){0.f, 0.f, 0.f, 0.f};

    const u16* aP = A + ((size_t)(r0 >> 4) + w * 2) * (KT12 * 512) + (size_t)lane * 8;
    const u16* bP = B + (size_t)(c0 >> 4) * (KT12 * 512) + (size_t)lane * 8;
#pragma unroll
    for (int dk = 0; dk < 12; ++dk) {
        short8 a0 = *(const short8*)(aP + dk * 512);
        short8 a1 = *(const short8*)(aP + (KT12 + dk) * 512);
#pragma unroll
        for (int mc = 0; mc < 4; ++mc) {
            short8 bf = *(const short8*)(bP + ((size_t)mc * KT12 + dk) * 512);
            acc[0][mc] = MFMA16(a0, bf, acc[0][mc], 0, 0, 0);
            acc[1][mc] = MFMA16(a1, bf, acc[1][mc], 0, 0, 0);
        }
    }

    if (bRow) {
#pragma unroll
        for (int ss = 0; ss < 2; ++ss) {
            f32x4 bv4 = *(const f32x4*)(bias + r0 + w * 32 + ss * 16 + quad * 4);
#pragma unroll
            for (int mc = 0; mc < 4; ++mc)
#pragma unroll
                for (int r = 0; r < 4; ++r) acc[ss][mc][r] += bv4[r];
        }
    } else {
#pragma unroll
        for (int mc = 0; mc < 4; ++mc) {
            float bc = bias[c0 + mc * 16 + l15] * bsc;
#pragma unroll
            for (int ss = 0; ss < 2; ++ss)
#pragma unroll
                for (int r = 0; r < 4; ++r) acc[ss][mc][r] += bc;
        }
    }

#pragma unroll
    for (int ss = 0; ss < 2; ++ss)
#pragma unroll
        for (int mc = 0; mc < 4; ++mc)
#pragma unroll
            for (int r = 0; r < 4; ++r)
                t16[(w * 32 + ss * 16 + quad * 4 + r) * 76 + mc * 16 + l15] = f2bf(acc[ss][mc][r]);
    __syncthreads();
#pragma unroll
    for (int p = 0; p < 4; ++p) {
        int g = p * 256 + t;  // [5:0]=lane' [6]=ktl [9:7]=rg
        int lan = g & 63, ktl = (g >> 6) & 1, rg = g >> 7;
        int row = rg * 16 + (lan & 15);
        int col = ktl * 32 + ((lan >> 4) & 3) * 8;
        uint4_ v = *(const uint4_*)(t16 + row * 76 + col);
        size_t dst = (((size_t)(r0 >> 4) + rg) * ktd + (c0 >> 5) + ktl) * 512 + (size_t)lan * 8;
        *(uint4_*)(O + dst) = v;
    }
}

// ---------------------------------------------------------------------------
// projf_sw: final projection. out[b][d][n] = sum_c Wf[d][c]*O[n][c] + bf.
// A=Wf (swizzle), B=o_sw (swizzle). 128x64 tile, fp32 row-major out.
// grid (48, BATCH), 256 threads.
// ---------------------------------------------------------------------------
__global__ __launch_bounds__(256) void projf_sw(
    const u16* __restrict__ wf_sw, const u16* __restrict__ osw,
    const float* __restrict__ bfp, float* __restrict__ out)
{
    __shared__ __align__(16) float t32[128 * 68];
    const int b = blockIdx.y, tile = blockIdx.x;
    const int r0 = (tile / 16) * 128, c0 = (tile % 16) * 64;
    const size_t TB = (size_t)NTOK * DIMC;

    const int t = threadIdx.x, w = t >> 6, lane = t & 63;
    const int quad = lane >> 4;

    f32x4 acc[2][4];
#pragma unroll
    for (int ss = 0; ss < 2; ++ss)
#pragma unroll
        for (int mc = 0; mc < 4; ++mc) acc[ss][mc] = (f32x4){0.f, 0.f, 0.f, 0.f};

    const u16* aP = wf_sw + ((size_t)(r0 >> 4) + w * 2) * (KT12 * 512) + (size_t)lane * 8;
    const u16* bP = osw + (size_t)b * TB + (size_t)(c0 >> 4) * (KT12 * 512) + (size_t)lane * 8;
#pragma unroll
    for (int dk = 0; dk < 12; ++dk) {
        short8 a0 = *(const short8*)(aP + dk * 512);
        short8 a1 = *(const short8*)(aP + (KT12 + dk) * 512);
#pragma unroll
        for (int mc = 0; mc < 4; ++mc) {
            short8 bf = *(const short8*)(bP + ((size_t)mc * KT12 + dk) * 512);
            acc[0][mc] = MFMA16(a0, bf, acc[0][mc], 0, 0, 0);
            acc[1][mc] = MFMA16(a1, bf, acc[1][mc], 0, 0, 0);
        }
    }
#pragma unroll
    for (int ss = 0; ss < 2; ++ss) {
        f32x4 bv4 = *(const f32x4*)(bfp + r0 + w * 32 + ss * 16 + quad * 4);
#pragma unroll
        for (int mc = 0; mc < 4; ++mc)
#pragma unroll
            for (int r = 0; r < 4; ++r) acc[ss][mc][r] += bv4[r];
    }

#pragma unroll
    for (int ss = 0; ss < 2; ++ss)
#pragma unroll
        for (int mc = 0; mc < 4; ++mc)
#pragma unroll
            for (int r = 0; r < 4; ++r)
                t32[(w * 32 + ss * 16 + quad * 4 + r) * 68 + mc * 16 + (lane & 15)] = acc[ss][mc][r];
    __syncthreads();
    float* Ob = out + (size_t)b * DIMC * NTOK;
#pragma unroll
    for (int p = 0; p < 8; ++p) {
        int g = p * 256 + t;
        int row = g >> 4, c4 = (g & 15) * 4;
        f32x4 v = *(const f32x4*)(t32 + row * 68 + c4);
        *(f32x4*)(Ob + (size_t)(r0 + row) * NTOK + c0 + c4) = v;
    }
}

// ---------------------------------------------------------------------------
// attn_lds: flash attention, 128 q/block (8 waves x 16 q), 512 threads.
// BOTH K and V double-buffered in LDS via async global_load_lds: 32-key
// tiles, 32 iterations, ONE barrier per tile. DMA for tile t+1 (6 frags/wave)
// issued right after the tile-t barrier -> has the whole tile's LDS-read+MFMA
// work (~3.5K cyc) to land before the end-of-tile __syncthreads (vmcnt drain).
// No global->VGPR loads on the compute path (round-1 lesson: those expose
// L2/HBM latency serially under AGPR-heavy register pressure).
// LDS: K 2x24KB + V 2x24KB + P 8x2.4KB = 115KB -> 1 block/CU, 8 waves/CU
// (equal to the AGPR-structural cap). Grid 256 = 1 block/CU exactly; bid
// mapping keeps all 8 blocks of a batch on one XCD (bid%8 const per batch)
// so K/V stream from that XCD's L2 (HBM total ~48MB).
// ---------------------------------------------------------------------------
__global__ __launch_bounds__(512, 2) void attn_lds(
    const u16* __restrict__ qsw, const u16* __restrict__ ksw,
    const u16* __restrict__ vsw, u16* __restrict__ osw)
{
    // u16 layout: kbuf0 [0,12288) kbuf1 [12288,24576)
    //             vbuf0 [24576,36864) vbuf1 [36864,49152)
    //             plds  [49152,58880): 8 waves x 16 rows x 76
    __shared__ __align__(16) u16 smem[58880];

    const int bid = blockIdx.x;
    const int b = (bid & 7) * 4 + ((bid >> 3) & 3);  // same-batch blocks share XCD
    const int qb = bid >> 5;                         // [0,8): 128-q block index
    const int t = threadIdx.x, w = t >> 6, lane = t & 63;
    const int l15 = lane & 15, quad = lane >> 4;
    const int rt = qb * 8 + w;                       // global 16-q row-tile

    const size_t TB = (size_t)NTOK * DIMC;
    const u16* kb = ksw + (size_t)b * TB;
    const u16* vb = vsw + (size_t)b * TB;
    u16* pw = smem + 49152 + w * 1216;

    // Q fragments resident (pre-scaled by scale*log2e at projection)
    short8 qf[12];
    const u16* qp = qsw + (size_t)b * TB + (size_t)rt * (KT12 * 512) + (size_t)lane * 8;
#pragma unroll
    for (int dk = 0; dk < 12; ++dk) qf[dk] = *(const short8*)(qp + dk * 512);

    f32x4 Oa[24];
#pragma unroll
    for (int i = 0; i < 24; ++i) Oa[i] = (f32x4){0.f, 0.f, 0.f, 0.f};
    float m_run[4], l_run[4];
#pragma unroll
    for (int r = 0; r < 4; ++r) { m_run[r] = -1e30f; l_run[r] = 0.f; }

    const int i0 = w * 3;  // this wave's 3 fragment indices (of 24)

    // prologue: DMA tile 0 into buffer 0
#pragma unroll
    for (int j = 0; j < 3; ++j) {
        int idx = i0 + j;
        GLD_LDS16(kb + (size_t)idx * 512 + lane * 8, smem + idx * 512);
        GLD_LDS16(vb + (size_t)(idx * 32) * 512 + lane * 8, smem + 24576 + idx * 512);
    }
    __syncthreads();

    for (int mt = 0; mt < 32; ++mt) {
        const int cur = mt & 1;
        u16* kcur = smem + cur * 12288;
        u16* vcur = smem + 24576 + cur * 12288;

        // issue DMA for tile mt+1 into the other buffer (lands during compute)
        if (mt < 31) {
            u16* knxt = smem + (cur ^ 1) * 12288;
            u16* vnxt = smem + 24576 + (cur ^ 1) * 12288;
#pragma unroll
            for (int j = 0; j < 3; ++j) {
                int idx = i0 + j;
                GLD_LDS16(kb + (size_t)(24 * (mt + 1) + idx) * 512 + lane * 8,
                          knxt + idx * 512);
                GLD_LDS16(vb + (size_t)(idx * 32 + mt + 1) * 512 + lane * 8,
                          vnxt + idx * 512);
            }
        }

        // ---- QK: S[16 q][32 keys] from LDS K frags ----
        f32x4 s[2];
        s[0] = (f32x4){0.f, 0.f, 0.f, 0.f};
        s[1] = (f32x4){0.f, 0.f, 0.f, 0.f};
        const u16* kfb = kcur + (size_t)lane * 8;
        __builtin_amdgcn_s_setprio(1);
#pragma unroll
        for (int dk = 0; dk < 12; ++dk) {
            short8 k0 = *(const short8*)(kfb + dk * 512);
            short8 k1 = *(const short8*)(kfb + (12 + dk) * 512);
            s[0] = MFMA16(qf[dk], k0, s[0], 0, 0, 0);
            s[1] = MFMA16(qf[dk], k1, s[1], 0, 0, 0);
        }
        __builtin_amdgcn_s_setprio(0);

        // ---- online softmax (log2-domain, deferred-max THR=8) ----
        float mx4[4];
#pragma unroll
        for (int r = 0; r < 4; ++r) {
            float mx = fmaxf(s[0][r], s[1][r]);
            mx = fmaxf(mx, __shfl_xor(mx, 1));
            mx = fmaxf(mx, __shfl_xor(mx, 2));
            mx = fmaxf(mx, __shfl_xor(mx, 4));
            mx = fmaxf(mx, __shfl_xor(mx, 8));
            mx4[r] = mx;
        }
        int grow = (mx4[0] > m_run[0] + 8.f) | (mx4[1] > m_run[1] + 8.f) |
                   (mx4[2] > m_run[2] + 8.f) | (mx4[3] > m_run[3] + 8.f);
        if (__any(grow)) {
            float alpha[4];
#pragma unroll
            for (int r = 0; r < 4; ++r) {
                float mn = fmaxf(m_run[r], mx4[r]);
                alpha[r] = exp2f(m_run[r] - mn);
                m_run[r] = mn;
                l_run[r] *= alpha[r];
            }
#pragma unroll
            for (int ci = 0; ci < 24; ++ci)
#pragma unroll
                for (int r = 0; r < 4; ++r) Oa[ci][r] *= alpha[r];
        }
#pragma unroll
        for (int r = 0; r < 4; ++r) {
            float ls = 0.f;
#pragma unroll
            for (int mc = 0; mc < 2; ++mc) {
                float p = exp2f(s[mc][r] - m_run[r]);
                u16 pb = f2bf(p);
                pw[(quad * 4 + r) * 76 + mc * 16 + l15] = pb;
                ls += bf2f(pb);  // denominator from rounded P -> exact normalization
            }
            ls += __shfl_xor(ls, 1);
            ls += __shfl_xor(ls, 2);
            ls += __shfl_xor(ls, 4);
            ls += __shfl_xor(ls, 8);
            l_run[r] += ls;
        }

        // ---- PV: P (wave-private LDS) x V (LDS), 24 independent chains ----
        short8 pa = *(const short8*)(pw + l15 * 76 + quad * 8);
        const u16* vfb = vcur + (size_t)lane * 8;
        __builtin_amdgcn_s_setprio(1);
#pragma unroll
        for (int ci = 0; ci < 24; ++ci) {
            short8 vf = *(const short8*)(vfb + ci * 512);
            Oa[ci] = MFMA16(pa, vf, Oa[ci], 0, 0, 0);
        }
        __builtin_amdgcn_s_setprio(0);

        __syncthreads();  // drains vmcnt: tile mt+1 landed; all reads of mt done
    }

    // ---- epilogue: normalize + wave-private transpose via pw + store ----
    float rl[4];
#pragma unroll
    for (int r = 0; r < 4; ++r) rl[r] = 1.f / l_run[r];
    u16* od = osw + (size_t)b * TB;
#pragma unroll
    for (int ch = 0; ch < 6; ++ch) {
#pragma unroll
        for (int cc = 0; cc < 4; ++cc)
#pragma unroll
            for (int r = 0; r < 4; ++r)
                pw[(quad * 4 + r) * 76 + cc * 16 + l15] = f2bf(Oa[ch * 4 + cc][r] * rl[r]);
#pragma unroll
        for (int ktl = 0; ktl < 2; ++ktl) {
            uint4_ vv = *(const uint4_*)(pw + l15 * 76 + ktl * 32 + quad * 8);
            size_t dst = ((size_t)rt * KT12 + ch * 2 + ktl) * 512 + (size_t)lane * 8;
            *(uint4_*)(od + dst) = vv;
        }
    }
}

extern "C" void kernel_launch(void* const* d_in, const int* in_sizes, int n_in,
                              void* d_out, int out_size, void* d_ws, size_t ws_size,
                              hipStream_t stream) {
    const float* rgb = (const float*)d_in[0];
    const float* ms  = (const float*)d_in[1];
    const float* Wq  = (const float*)d_in[2];
    const float* bq  = (const float*)d_in[3];
    const float* Wk  = (const float*)d_in[4];
    const float* bk  = (const float*)d_in[5];
    const float* Wv  = (const float*)d_in[6];
    const float* bv  = (const float*)d_in[7];
    const float* Wf  = (const float*)d_in[8];
    const float* bf_ = (const float*)d_in[9];
    float* outp = (float*)d_out;

    const float SC2 = 0.05103103630798288f * 1.4426950408889634f;  // scale*log2e

    const size_t TN = (size_t)BATCH * NTOK * DIMC;  // 12.58M elems
    const size_t WN = (size_t)DIMC * DIMC;          // 147456
    u16* rgb_sw = (u16*)d_ws;         // swizzle R=n K=c
    u16* ms_sw  = rgb_sw + TN;
    u16* q_sw   = ms_sw + TN;         // R=n K=d (pre-scaled)
    u16* k_sw   = q_sw + TN;          // R=m K=d
    u16* v_sw   = k_sw + TN;          // R=c K=m (KT=32)
    u16* o_sw   = v_sw + TN;          // R=n K=c
    u16* w_sw   = o_sw + TN;          // Wq,Wk,Wv,Wf swizzled concat
    // total ws: 6*25.2MB + 1.2MB = 152 MB

    wcvt_sw<<<dim3(72, 4), 256, 0, stream>>>(Wq, Wk, Wv, Wf, w_sw, SC2);
    transpose_sw<<<dim3(16, 6, BATCH), 256, 0, stream>>>(rgb, rgb_sw);
    transpose_sw<<<dim3(16, 6, BATCH), 256, 0, stream>>>(ms, ms_sw);

    proj3_sw<<<dim3(48, 3, BATCH), 256, 0, stream>>>(
        rgb_sw, ms_sw, w_sw, q_sw, k_sw, v_sw, bq, bk, bv, SC2);

    attn_lds<<<dim3(256), 512, 0, stream>>>(q_sw, k_sw, v_sw, o_sw);

    projf_sw<<<dim3(48, BATCH), 256, 0, stream>>>(w_sw + 3 * WN, o_sw, bf_, outp);
}

// Round 4
// 342.165 us; speedup vs baseline: 1.6899x; 1.0067x over previous
//
#include <hip/hip_runtime.h>

#define DIMC 384
#define NTOK 1024
#define BATCH 32
#define KT12 12

using short8 = __attribute__((ext_vector_type(8))) short;
using f32x4  = __attribute__((ext_vector_type(4))) float;
using uint4_ = __attribute__((ext_vector_type(4))) unsigned int;
typedef unsigned short u16;

#define MFMA16 __builtin_amdgcn_mfma_f32_16x16x32_bf16

// async global->LDS, 16B/lane. LDS dest = wave-uniform base + lane*16.
#define GLD_LDS16(gp, lp)                                                     \
    __builtin_amdgcn_global_load_lds(                                         \
        (const __attribute__((address_space(1))) void*)(gp),                  \
        (__attribute__((address_space(3))) void*)(lp), 16, 0, 0)

__device__ __forceinline__ u16 f2bf(float f) {
    unsigned int u = __builtin_bit_cast(unsigned int, f);
    u += 0x7FFFu + ((u >> 16) & 1u);
    return (u16)(u >> 16);
}
__device__ __forceinline__ float bf2f(u16 h) {
    unsigned int u = ((unsigned int)h) << 16;
    return __builtin_bit_cast(float, u);
}

// Unified fragment-contiguous swizzle for matrix M[R][K] (K = contraction):
//   flat = ((r>>4)*KT + (k>>5))*512 + (((k>>3)&3)*16 + (r&15))*8 + (k&7)
// One MFMA A/B fragment (rt, kt) = 1 KB contiguous at ((rt*KT+kt)*64+lane)*8.

// ---------------------------------------------------------------------------
// transpose_sw: X (b, c, n) fp32 -> X_sw (b, swizzle R=n K=c) bf16.
// grid (16, 6, BATCH), 256 threads.
// ---------------------------------------------------------------------------
__global__ __launch_bounds__(256) void transpose_sw(
    const float* __restrict__ X, u16* __restrict__ Xsw)
{
    __shared__ float tl[64 * 65];
    const int b = blockIdx.z, n0 = blockIdx.x * 64, c0 = blockIdx.y * 64;
    const int t = threadIdx.x;

#pragma unroll
    for (int p = 0; p < 4; ++p) {
        int idx = p * 256 + t;
        int c = idx >> 4, n4 = (idx & 15) * 4;
        f32x4 v = *(const f32x4*)(X + ((size_t)b * DIMC + c0 + c) * NTOK + n0 + n4);
#pragma unroll
        for (int i = 0; i < 4; ++i) tl[c * 65 + n4 + i] = v[i];
    }
    __syncthreads();
    u16* dstb = Xsw + (size_t)b * NTOK * DIMC;
#pragma unroll
    for (int p = 0; p < 2; ++p) {
        int g = p * 256 + t;  // [3:0]=n15 [5:4]=quad [6]=ktl [8:7]=rg
        int n15 = g & 15, quad = (g >> 4) & 3, ktl = (g >> 6) & 1, rg = g >> 7;
        int c8 = ktl * 32 + quad * 8;
        int nl = rg * 16 + n15;
        uint4_ pk;
#pragma unroll
        for (int i = 0; i < 4; ++i) {
            u16 lo = f2bf(tl[(c8 + 2 * i) * 65 + nl]);
            u16 hi = f2bf(tl[(c8 + 2 * i + 1) * 65 + nl]);
            pk[i] = (unsigned)lo | ((unsigned)hi << 16);
        }
        size_t dst = (((size_t)(n0 >> 4) + rg) * KT12 + (c0 >> 5) + ktl) * 512 + (size_t)(g & 63) * 8;
        *(uint4_*)(dstb + dst) = pk;
    }
}

// ---------------------------------------------------------------------------
// wcvt_sw: 4 weight matrices (384x384 fp32 [d][c]) -> swizzle bf16 (R=d, K=c),
// concatenated. Matrix 0 (Wq) pre-scaled by scale*log2e. grid (72,4), 256 thr.
// ---------------------------------------------------------------------------
__global__ __launch_bounds__(256) void wcvt_sw(
    const float* __restrict__ w0, const float* __restrict__ w1,
    const float* __restrict__ w2, const float* __restrict__ w3,
    u16* __restrict__ dst, float s0)
{
    const float* srcs[4] = {w0, w1, w2, w3};
    const float* s = srcs[blockIdx.y];
    float scl = (blockIdx.y == 0) ? s0 : 1.0f;
    u16* d = dst + (size_t)blockIdx.y * DIMC * DIMC;
    int e0 = (blockIdx.x * 256 + threadIdx.x) * 8;
    int dd = e0 / DIMC, c8 = e0 % DIMC;
    f32x4 a = *(const f32x4*)(s + e0);
    f32x4 b2 = *(const f32x4*)(s + e0 + 4);
    uint4_ pk;
    pk[0] = (unsigned)f2bf(a[0] * scl) | ((unsigned)f2bf(a[1] * scl) << 16);
    pk[1] = (unsigned)f2bf(a[2] * scl) | ((unsigned)f2bf(a[3] * scl) << 16);
    pk[2] = (unsigned)f2bf(b2[0] * scl) | ((unsigned)f2bf(b2[1] * scl) << 16);
    pk[3] = (unsigned)f2bf(b2[2] * scl) | ((unsigned)f2bf(b2[3] * scl) << 16);
    size_t off = ((size_t)(dd >> 4) * KT12 + (c8 >> 5)) * 512 +
                 (size_t)((((c8 >> 3) & 3) * 16 + (dd & 15)) * 8);
    *(uint4_*)(d + off) = pk;
}

// ---------------------------------------------------------------------------
// proj3_g: q/k/v projections, m97-style staged GEMM. 128x128 output tile,
// 4 waves (each 64x64 = 4x4 frags, 64 AGPR), K-step 32 (12 steps).
// A+B chunks (8+8 frags = 16KB) double-buffered via global_load_lds; one
// barrier per K-step; 3 blocks/CU (42.5KB LDS) -> 3 independent barrier
// domains per CU overlap each other's vmcnt drains (round-1/3 lesson:
// direct global->MFMA fragment loads are 2-3x slower than LDS-fed).
// Grid 2304 x 256 thr, 1-D: b = bid&31 -> all 72 blocks of a batch on
// XCD b%8 (activations+weights L2-local).
//   s=0: A=rgb_sw B=Wq  -> q_sw (ktd=12, col bias x scale)
//   s=1: A=ms_sw  B=Wk  -> k_sw (ktd=12, col bias)
//   s=2: A=Wv     B=ms_sw -> v_sw (ktd=32, row bias)
// ---------------------------------------------------------------------------
__global__ __launch_bounds__(256, 3) void proj3_g(
    const u16* __restrict__ rgb_sw, const u16* __restrict__ ms_sw,
    const u16* __restrict__ w_sw,
    u16* __restrict__ q_sw, u16* __restrict__ k_sw, u16* __restrict__ v_sw,
    const float* __restrict__ bq, const float* __restrict__ bk,
    const float* __restrict__ bv, float s0)
{
    // u16 layout: stA0 [0,4096) stA1 [4096,8192) stB0 [8192,12288)
    //             stB1 [12288,16384) pw 4x1216 [16384,21248)
    __shared__ __align__(16) u16 smem[21248];

    const int bid = blockIdx.x;
    const int b = bid & 31;
    const int rr = bid >> 5;              // [0,72)
    const int s = rr % 3, tile = rr / 3;  // tile in [0,24)
    const size_t TB = (size_t)NTOK * DIMC, WN = (size_t)DIMC * DIMC;
    const u16 *A, *B; u16* O; const float* bias;
    int ktd, bRow, r0, c0; float bsc = 1.f;
    if (s == 0) {
        A = rgb_sw + b * TB; B = w_sw; O = q_sw + b * TB; bias = bq;
        ktd = 12; bRow = 0; r0 = (tile & 7) * 128; c0 = (tile >> 3) * 128; bsc = s0;
    } else if (s == 1) {
        A = ms_sw + b * TB; B = w_sw + WN; O = k_sw + b * TB; bias = bk;
        ktd = 12; bRow = 0; r0 = (tile & 7) * 128; c0 = (tile >> 3) * 128;
    } else {
        A = w_sw + 2 * WN; B = ms_sw + b * TB; O = v_sw + b * TB; bias = bv;
        ktd = 32; bRow = 1; r0 = (tile % 3) * 128; c0 = (tile / 3) * 128;
    }

    const int t = threadIdx.x, w = t >> 6, lane = t & 63;
    const int l15 = lane & 15, quad = lane >> 4;
    const int wr = w >> 1, wc = w & 1;    // wave quadrant (rows, cols)
    const int rt0 = r0 >> 4, ct0 = c0 >> 4;
    u16* pw = smem + 16384 + w * 1216;

    f32x4 acc[4][4];
#pragma unroll
    for (int ai = 0; ai < 4; ++ai)
#pragma unroll
        for (int bj = 0; bj < 4; ++bj) acc[ai][bj] = (f32x4){0.f, 0.f, 0.f, 0.f};

    // prologue: stage K-step 0 into buffer 0 (wave w owns frags 2w, 2w+1)
    {
        const u16* As = A + ((size_t)(rt0 + 2 * w) * KT12) * 512 + (size_t)lane * 8;
        GLD_LDS16(As, smem + (2 * w) * 512);
        GLD_LDS16(As + KT12 * 512, smem + (2 * w + 1) * 512);
        const u16* Bs = B + ((size_t)(ct0 + 2 * w) * KT12) * 512 + (size_t)lane * 8;
        GLD_LDS16(Bs, smem + 8192 + (2 * w) * 512);
        GLD_LDS16(Bs + KT12 * 512, smem + 8192 + (2 * w + 1) * 512);
    }
    __syncthreads();

    for (int kt = 0; kt < 12; ++kt) {
        const int cur = kt & 1;
        if (kt < 11) {
            u16* dA = smem + (cur ^ 1) * 4096;
            u16* dB = smem + 8192 + (cur ^ 1) * 4096;
            const u16* As = A + ((size_t)(rt0 + 2 * w) * KT12 + kt + 1) * 512 + (size_t)lane * 8;
            GLD_LDS16(As, dA + (2 * w) * 512);
            GLD_LDS16(As + KT12 * 512, dA + (2 * w + 1) * 512);
            const u16* Bs = B + ((size_t)(ct0 + 2 * w) * KT12 + kt + 1) * 512 + (size_t)lane * 8;
            GLD_LDS16(Bs, dB + (2 * w) * 512);
            GLD_LDS16(Bs + KT12 * 512, dB + (2 * w + 1) * 512);
        }
        const u16* sA = smem + cur * 4096 + (size_t)(wr * 4) * 512 + (size_t)lane * 8;
        const u16* sB = smem + 8192 + cur * 4096 + (size_t)(wc * 4) * 512 + (size_t)lane * 8;
        short8 aF[4], bF[4];
#pragma unroll
        for (int ai = 0; ai < 4; ++ai) aF[ai] = *(const short8*)(sA + ai * 512);
#pragma unroll
        for (int bj = 0; bj < 4; ++bj) bF[bj] = *(const short8*)(sB + bj * 512);
        __builtin_amdgcn_s_setprio(1);
#pragma unroll
        for (int ai = 0; ai < 4; ++ai)
#pragma unroll
            for (int bj = 0; bj < 4; ++bj)
                acc[ai][bj] = MFMA16(aF[ai], bF[bj], acc[ai][bj], 0, 0, 0);
        __builtin_amdgcn_s_setprio(0);
        __syncthreads();  // drains vmcnt: next chunk landed; reads of cur done
    }

    // bias
    if (bRow) {
#pragma unroll
        for (int ai = 0; ai < 4; ++ai) {
            f32x4 bv4 = *(const f32x4*)(bias + r0 + wr * 64 + ai * 16 + quad * 4);
#pragma unroll
            for (int bj = 0; bj < 4; ++bj)
#pragma unroll
                for (int r = 0; r < 4; ++r) acc[ai][bj][r] += bv4[r];
        }
    } else {
#pragma unroll
        for (int bj = 0; bj < 4; ++bj) {
            float bc = bias[c0 + wc * 64 + bj * 16 + l15] * bsc;
#pragma unroll
            for (int ai = 0; ai < 4; ++ai)
#pragma unroll
                for (int r = 0; r < 4; ++r) acc[ai][bj][r] += bc;
        }
    }

    // epilogue: per-wave swizzled bf16 store (wave-private pw, no barriers)
#pragma unroll
    for (int ai = 0; ai < 4; ++ai) {
#pragma unroll
        for (int bj = 0; bj < 4; ++bj)
#pragma unroll
            for (int r = 0; r < 4; ++r)
                pw[(quad * 4 + r) * 76 + bj * 16 + l15] = f2bf(acc[ai][bj][r]);
        const int rt = rt0 + wr * 4 + ai;
        const int kb0 = (c0 + wc * 64) >> 5;
#pragma unroll
        for (int ktl = 0; ktl < 2; ++ktl) {
            uint4_ v = *(const uint4_*)(pw + l15 * 76 + ktl * 32 + quad * 8);
            *(uint4_*)(O + ((size_t)rt * ktd + kb0 + ktl) * 512 + (size_t)lane * 8) = v;
        }
    }
}

// ---------------------------------------------------------------------------
// projf_g: final projection, same staged-GEMM skeleton as proj3_g.
// out[b][d][n] = sum_c Wf[d][c]*O[n][c] + bf. A=Wf, B=o_sw (both KT12
// swizzle). fp32 direct stores (16 lanes = 64B packed segments).
// grid 768 x 256 thr: b = bid&31, tile = bid>>5 in [0,24).
// ---------------------------------------------------------------------------
__global__ __launch_bounds__(256, 3) void projf_g(
    const u16* __restrict__ wf_sw, const u16* __restrict__ osw,
    const float* __restrict__ bfp, float* __restrict__ out)
{
    __shared__ __align__(16) u16 smem[16384];
    const int bid = blockIdx.x;
    const int b = bid & 31, tile = bid >> 5;  // [0,24)
    const int r0 = (tile % 3) * 128, c0 = (tile / 3) * 128;
    const size_t TB = (size_t)NTOK * DIMC;

    const int t = threadIdx.x, w = t >> 6, lane = t & 63;
    const int l15 = lane & 15, quad = lane >> 4;
    const int wr = w >> 1, wc = w & 1;
    const int rt0 = r0 >> 4, ct0 = c0 >> 4;
    const u16* A = wf_sw;
    const u16* B = osw + (size_t)b * TB;

    f32x4 acc[4][4];
#pragma unroll
    for (int ai = 0; ai < 4; ++ai)
#pragma unroll
        for (int bj = 0; bj < 4; ++bj) acc[ai][bj] = (f32x4){0.f, 0.f, 0.f, 0.f};

    {
        const u16* As = A + ((size_t)(rt0 + 2 * w) * KT12) * 512 + (size_t)lane * 8;
        GLD_LDS16(As, smem + (2 * w) * 512);
        GLD_LDS16(As + KT12 * 512, smem + (2 * w + 1) * 512);
        const u16* Bs = B + ((size_t)(ct0 + 2 * w) * KT12) * 512 + (size_t)lane * 8;
        GLD_LDS16(Bs, smem + 8192 + (2 * w) * 512);
        GLD_LDS16(Bs + KT12 * 512, smem + 8192 + (2 * w + 1) * 512);
    }
    __syncthreads();

    for (int kt = 0; kt < 12; ++kt) {
        const int cur = kt & 1;
        if (kt < 11) {
            u16* dA = smem + (cur ^ 1) * 4096;
            u16* dB = smem + 8192 + (cur ^ 1) * 4096;
            const u16* As = A + ((size_t)(rt0 + 2 * w) * KT12 + kt + 1) * 512 + (size_t)lane * 8;
            GLD_LDS16(As, dA + (2 * w) * 512);
            GLD_LDS16(As + KT12 * 512, dA + (2 * w + 1) * 512);
            const u16* Bs = B + ((size_t)(ct0 + 2 * w) * KT12 + kt + 1) * 512 + (size_t)lane * 8;
            GLD_LDS16(Bs, dB + (2 * w) * 512);
            GLD_LDS16(Bs + KT12 * 512, dB + (2 * w + 1) * 512);
        }
        const u16* sA = smem + cur * 4096 + (size_t)(wr * 4) * 512 + (size_t)lane * 8;
        const u16* sB = smem + 8192 + cur * 4096 + (size_t)(wc * 4) * 512 + (size_t)lane * 8;
        short8 aF[4], bF[4];
#pragma unroll
        for (int ai = 0; ai < 4; ++ai) aF[ai] = *(const short8*)(sA + ai * 512);
#pragma unroll
        for (int bj = 0; bj < 4; ++bj) bF[bj] = *(const short8*)(sB + bj * 512);
        __builtin_amdgcn_s_setprio(1);
#pragma unroll
        for (int ai = 0; ai < 4; ++ai)
#pragma unroll
            for (int bj = 0; bj < 4; ++bj)
                acc[ai][bj] = MFMA16(aF[ai], bF[bj], acc[ai][bj], 0, 0, 0);
        __builtin_amdgcn_s_setprio(0);
        __syncthreads();
    }

    float* Ob = out + (size_t)b * DIMC * NTOK;
#pragma unroll
    for (int ai = 0; ai < 4; ++ai) {
        f32x4 bv4 = *(const f32x4*)(bfp + r0 + wr * 64 + ai * 16 + quad * 4);
#pragma unroll
        for (int bj = 0; bj < 4; ++bj) {
            const int col = c0 + wc * 64 + bj * 16 + l15;
#pragma unroll
            for (int r = 0; r < 4; ++r) {
                const int row = r0 + wr * 64 + ai * 16 + quad * 4 + r;
                Ob[(size_t)row * NTOK + col] = acc[ai][bj][r] + bv4[r];
            }
        }
    }
}

// ---------------------------------------------------------------------------
// attn_lds: flash attention, 128 q/block (8 waves x 16 q), 512 threads.
// BOTH K and V double-buffered in LDS via async global_load_lds: 32-key
// tiles, 32 iterations, ONE barrier per tile. DMA for tile t+1 (6 frags/wave)
// issued right after the tile-t barrier -> has the whole tile's LDS-read+MFMA
// work to land before the end-of-tile __syncthreads (vmcnt drain).
// LDS: K 2x24KB + V 2x24KB + P 8x2.4KB = 115KB -> 1 block/CU, 8 waves/CU.
// Grid 256 = 1 block/CU; bid mapping keeps all 8 blocks of a batch on one
// XCD so K/V stream from that XCD's L2 (measured FETCH 37MB, conflicts 0).
// ---------------------------------------------------------------------------
__global__ __launch_bounds__(512, 2) void attn_lds(
    const u16* __restrict__ qsw, const u16* __restrict__ ksw,
    const u16* __restrict__ vsw, u16* __restrict__ osw)
{
    // u16 layout: kbuf0 [0,12288) kbuf1 [12288,24576)
    //             vbuf0 [24576,36864) vbuf1 [36864,49152)
    //             plds  [49152,58880): 8 waves x 16 rows x 76
    __shared__ __align__(16) u16 smem[58880];

    const int bid = blockIdx.x;
    const int b = (bid & 7) * 4 + ((bid >> 3) & 3);  // same-batch blocks share XCD
    const int qb = bid >> 5;                         // [0,8): 128-q block index
    const int t = threadIdx.x, w = t >> 6, lane = t & 63;
    const int l15 = lane & 15, quad = lane >> 4;
    const int rt = qb * 8 + w;                       // global 16-q row-tile

    const size_t TB = (size_t)NTOK * DIMC;
    const u16* kb = ksw + (size_t)b * TB;
    const u16* vb = vsw + (size_t)b * TB;
    u16* pw = smem + 49152 + w * 1216;

    // Q fragments resident (pre-scaled by scale*log2e at projection)
    short8 qf[12];
    const u16* qp = qsw + (size_t)b * TB + (size_t)rt * (KT12 * 512) + (size_t)lane * 8;
#pragma unroll
    for (int dk = 0; dk < 12; ++dk) qf[dk] = *(const short8*)(qp + dk * 512);

    f32x4 Oa[24];
#pragma unroll
    for (int i = 0; i < 24; ++i) Oa[i] = (f32x4){0.f, 0.f, 0.f, 0.f};
    float m_run[4], l_run[4];
#pragma unroll
    for (int r = 0; r < 4; ++r) { m_run[r] = -1e30f; l_run[r] = 0.f; }

    const int i0 = w * 3;  // this wave's 3 fragment indices (of 24)

    // prologue: DMA tile 0 into buffer 0
#pragma unroll
    for (int j = 0; j < 3; ++j) {
        int idx = i0 + j;
        GLD_LDS16(kb + (size_t)idx * 512 + lane * 8, smem + idx * 512);
        GLD_LDS16(vb + (size_t)(idx * 32) * 512 + lane * 8, smem + 24576 + idx * 512);
    }
    __syncthreads();

    for (int mt = 0; mt < 32; ++mt) {
        const int cur = mt & 1;
        u16* kcur = smem + cur * 12288;
        u16* vcur = smem + 24576 + cur * 12288;

        // issue DMA for tile mt+1 into the other buffer (lands during compute)
        if (mt < 31) {
            u16* knxt = smem + (cur ^ 1) * 12288;
            u16* vnxt = smem + 24576 + (cur ^ 1) * 12288;
#pragma unroll
            for (int j = 0; j < 3; ++j) {
                int idx = i0 + j;
                GLD_LDS16(kb + (size_t)(24 * (mt + 1) + idx) * 512 + lane * 8,
                          knxt + idx * 512);
                GLD_LDS16(vb + (size_t)(idx * 32 + mt + 1) * 512 + lane * 8,
                          vnxt + idx * 512);
            }
        }

        // ---- QK: S[16 q][32 keys] from LDS K frags ----
        f32x4 s[2];
        s[0] = (f32x4){0.f, 0.f, 0.f, 0.f};
        s[1] = (f32x4){0.f, 0.f, 0.f, 0.f};
        const u16* kfb = kcur + (size_t)lane * 8;
        __builtin_amdgcn_s_setprio(1);
#pragma unroll
        for (int dk = 0; dk < 12; ++dk) {
            short8 k0 = *(const short8*)(kfb + dk * 512);
            short8 k1 = *(const short8*)(kfb + (12 + dk) * 512);
            s[0] = MFMA16(qf[dk], k0, s[0], 0, 0, 0);
            s[1] = MFMA16(qf[dk], k1, s[1], 0, 0, 0);
        }
        __builtin_amdgcn_s_setprio(0);

        // ---- online softmax (log2-domain, deferred-max THR=8) ----
        float mx4[4];
#pragma unroll
        for (int r = 0; r < 4; ++r) {
            float mx = fmaxf(s[0][r], s[1][r]);
            mx = fmaxf(mx, __shfl_xor(mx, 1));
            mx = fmaxf(mx, __shfl_xor(mx, 2));
            mx = fmaxf(mx, __shfl_xor(mx, 4));
            mx = fmaxf(mx, __shfl_xor(mx, 8));
            mx4[r] = mx;
        }
        int grow = (mx4[0] > m_run[0] + 8.f) | (mx4[1] > m_run[1] + 8.f) |
                   (mx4[2] > m_run[2] + 8.f) | (mx4[3] > m_run[3] + 8.f);
        if (__any(grow)) {
            float alpha[4];
#pragma unroll
            for (int r = 0; r < 4; ++r) {
                float mn = fmaxf(m_run[r], mx4[r]);
                alpha[r] = exp2f(m_run[r] - mn);
                m_run[r] = mn;
                l_run[r] *= alpha[r];
            }
#pragma unroll
            for (int ci = 0; ci < 24; ++ci)
#pragma unroll
                for (int r = 0; r < 4; ++r) Oa[ci][r] *= alpha[r];
        }
#pragma unroll
        for (int r = 0; r < 4; ++r) {
            float ls = 0.f;
#pragma unroll
            for (int mc = 0; mc < 2; ++mc) {
                float p = exp2f(s[mc][r] - m_run[r]);
                u16 pb = f2bf(p);
                pw[(quad * 4 + r) * 76 + mc * 16 + l15] = pb;
                ls += bf2f(pb);  // denominator from rounded P -> exact normalization
            }
            ls += __shfl_xor(ls, 1);
            ls += __shfl_xor(ls, 2);
            ls += __shfl_xor(ls, 4);
            ls += __shfl_xor(ls, 8);
            l_run[r] += ls;
        }

        // ---- PV: P (wave-private LDS) x V (LDS), 24 independent chains ----
        short8 pa = *(const short8*)(pw + l15 * 76 + quad * 8);
        const u16* vfb = vcur + (size_t)lane * 8;
        __builtin_amdgcn_s_setprio(1);
#pragma unroll
        for (int ci = 0; ci < 24; ++ci) {
            short8 vf = *(const short8*)(vfb + ci * 512);
            Oa[ci] = MFMA16(pa, vf, Oa[ci], 0, 0, 0);
        }
        __builtin_amdgcn_s_setprio(0);

        __syncthreads();  // drains vmcnt: tile mt+1 landed; all reads of mt done
    }

    // ---- epilogue: normalize + wave-private transpose via pw + store ----
    float rl[4];
#pragma unroll
    for (int r = 0; r < 4; ++r) rl[r] = 1.f / l_run[r];
    u16* od = osw + (size_t)b * TB;
#pragma unroll
    for (int ch = 0; ch < 6; ++ch) {
#pragma unroll
        for (int cc = 0; cc < 4; ++cc)
#pragma unroll
            for (int r = 0; r < 4; ++r)
                pw[(quad * 4 + r) * 76 + cc * 16 + l15] = f2bf(Oa[ch * 4 + cc][r] * rl[r]);
#pragma unroll
        for (int ktl = 0; ktl < 2; ++ktl) {
            uint4_ vv = *(const uint4_*)(pw + l15 * 76 + ktl * 32 + quad * 8);
            size_t dst = ((size_t)rt * KT12 + ch * 2 + ktl) * 512 + (size_t)lane * 8;
            *(uint4_*)(od + dst) = vv;
        }
    }
}

extern "C" void kernel_launch(void* const* d_in, const int* in_sizes, int n_in,
                              void* d_out, int out_size, void* d_ws, size_t ws_size,
                              hipStream_t stream) {
    const float* rgb = (const float*)d_in[0];
    const float* ms  = (const float*)d_in[1];
    const float* Wq  = (const float*)d_in[2];
    const float* bq  = (const float*)d_in[3];
    const float* Wk  = (const float*)d_in[4];
    const float* bk  = (const float*)d_in[5];
    const float* Wv  = (const float*)d_in[6];
    const float* bv  = (const float*)d_in[7];
    const float* Wf  = (const float*)d_in[8];
    const float* bf_ = (const float*)d_in[9];
    float* outp = (float*)d_out;

    const float SC2 = 0.05103103630798288f * 1.4426950408889634f;  // scale*log2e

    const size_t TN = (size_t)BATCH * NTOK * DIMC;  // 12.58M elems
    const size_t WN = (size_t)DIMC * DIMC;          // 147456
    u16* rgb_sw = (u16*)d_ws;         // swizzle R=n K=c
    u16* ms_sw  = rgb_sw + TN;
    u16* q_sw   = ms_sw + TN;         // R=n K=d (pre-scaled)
    u16* k_sw   = q_sw + TN;          // R=m K=d
    u16* v_sw   = k_sw + TN;          // R=c K=m (KT=32)
    u16* o_sw   = v_sw + TN;          // R=n K=c
    u16* w_sw   = o_sw + TN;          // Wq,Wk,Wv,Wf swizzled concat
    // total ws: 6*25.2MB + 1.2MB = 152 MB

    wcvt_sw<<<dim3(72, 4), 256, 0, stream>>>(Wq, Wk, Wv, Wf, w_sw, SC2);
    transpose_sw<<<dim3(16, 6, BATCH), 256, 0, stream>>>(rgb, rgb_sw);
    transpose_sw<<<dim3(16, 6, BATCH), 256, 0, stream>>>(ms, ms_sw);

    proj3_g<<<dim3(2304), 256, 0, stream>>>(
        rgb_sw, ms_sw, w_sw, q_sw, k_sw, v_sw, bq, bk, bv, SC2);

    attn_lds<<<dim3(256), 512, 0, stream>>>(q_sw, k_sw, v_sw, o_sw);

    projf_g<<<dim3(768), 256, 0, stream>>>(w_sw + 3 * WN, o_sw, bf_, outp);
}

// Round 5
// 329.798 us; speedup vs baseline: 1.7533x; 1.0375x over previous
//
#include <hip/hip_runtime.h>

#define DIMC 384
#define NTOK 1024
#define BATCH 32
#define KT12 12

using short8 = __attribute__((ext_vector_type(8))) short;
using f32x4  = __attribute__((ext_vector_type(4))) float;
using uint4_ = __attribute__((ext_vector_type(4))) unsigned int;
typedef unsigned short u16;

#define MFMA16 __builtin_amdgcn_mfma_f32_16x16x32_bf16

// async global->LDS, 16B/lane. LDS dest = wave-uniform base + lane*16.
#define GLD_LDS16(gp, lp)                                                     \
    __builtin_amdgcn_global_load_lds(                                         \
        (const __attribute__((address_space(1))) void*)(gp),                  \
        (__attribute__((address_space(3))) void*)(lp), 16, 0, 0)

__device__ __forceinline__ u16 f2bf(float f) {
    unsigned int u = __builtin_bit_cast(unsigned int, f);
    u += 0x7FFFu + ((u >> 16) & 1u);
    return (u16)(u >> 16);
}
__device__ __forceinline__ float bf2f(u16 h) {
    unsigned int u = ((unsigned int)h) << 16;
    return __builtin_bit_cast(float, u);
}

// Unified fragment-contiguous swizzle for matrix M[R][K] (K = contraction):
//   flat = ((r>>4)*KT + (k>>5))*512 + (((k>>3)&3)*16 + (r&15))*8 + (k&7)
// One MFMA A/B fragment (rt, kt) = 1 KB contiguous at ((rt*KT+kt)*64+lane)*8.

// ---------------------------------------------------------------------------
// transpose_sw: X (b, c, n) fp32 -> X_sw (b, swizzle R=n K=c) bf16.
// grid (16, 6, 2*BATCH): z<32 -> rgb, z>=32 -> ms (one launch for both).
// ---------------------------------------------------------------------------
__global__ __launch_bounds__(256) void transpose_sw(
    const float* __restrict__ X0, u16* __restrict__ X0sw,
    const float* __restrict__ X1, u16* __restrict__ X1sw)
{
    __shared__ float tl[64 * 65];
    const int z = blockIdx.z;
    const float* X = (z < BATCH) ? X0 : X1;
    u16* Xsw = (z < BATCH) ? X0sw : X1sw;
    const int b = z & 31, n0 = blockIdx.x * 64, c0 = blockIdx.y * 64;
    const int t = threadIdx.x;

#pragma unroll
    for (int p = 0; p < 4; ++p) {
        int idx = p * 256 + t;
        int c = idx >> 4, n4 = (idx & 15) * 4;
        f32x4 v = *(const f32x4*)(X + ((size_t)b * DIMC + c0 + c) * NTOK + n0 + n4);
#pragma unroll
        for (int i = 0; i < 4; ++i) tl[c * 65 + n4 + i] = v[i];
    }
    __syncthreads();
    u16* dstb = Xsw + (size_t)b * NTOK * DIMC;
#pragma unroll
    for (int p = 0; p < 2; ++p) {
        int g = p * 256 + t;  // [3:0]=n15 [5:4]=quad [6]=ktl [8:7]=rg
        int n15 = g & 15, quad = (g >> 4) & 3, ktl = (g >> 6) & 1, rg = g >> 7;
        int c8 = ktl * 32 + quad * 8;
        int nl = rg * 16 + n15;
        uint4_ pk;
#pragma unroll
        for (int i = 0; i < 4; ++i) {
            u16 lo = f2bf(tl[(c8 + 2 * i) * 65 + nl]);
            u16 hi = f2bf(tl[(c8 + 2 * i + 1) * 65 + nl]);
            pk[i] = (unsigned)lo | ((unsigned)hi << 16);
        }
        size_t dst = (((size_t)(n0 >> 4) + rg) * KT12 + (c0 >> 5) + ktl) * 512 + (size_t)(g & 63) * 8;
        *(uint4_*)(dstb + dst) = pk;
    }
}

// ---------------------------------------------------------------------------
// wcvt_sw: 4 weight matrices (384x384 fp32 [d][c]) -> swizzle bf16 (R=d, K=c),
// concatenated. Matrix 0 (Wq) pre-scaled by scale*log2e. grid (72,4), 256 thr.
// ---------------------------------------------------------------------------
__global__ __launch_bounds__(256) void wcvt_sw(
    const float* __restrict__ w0, const float* __restrict__ w1,
    const float* __restrict__ w2, const float* __restrict__ w3,
    u16* __restrict__ dst, float s0)
{
    const float* srcs[4] = {w0, w1, w2, w3};
    const float* s = srcs[blockIdx.y];
    float scl = (blockIdx.y == 0) ? s0 : 1.0f;
    u16* d = dst + (size_t)blockIdx.y * DIMC * DIMC;
    int e0 = (blockIdx.x * 256 + threadIdx.x) * 8;
    int dd = e0 / DIMC, c8 = e0 % DIMC;
    f32x4 a = *(const f32x4*)(s + e0);
    f32x4 b2 = *(const f32x4*)(s + e0 + 4);
    uint4_ pk;
    pk[0] = (unsigned)f2bf(a[0] * scl) | ((unsigned)f2bf(a[1] * scl) << 16);
    pk[1] = (unsigned)f2bf(a[2] * scl) | ((unsigned)f2bf(a[3] * scl) << 16);
    pk[2] = (unsigned)f2bf(b2[0] * scl) | ((unsigned)f2bf(b2[1] * scl) << 16);
    pk[3] = (unsigned)f2bf(b2[2] * scl) | ((unsigned)f2bf(b2[3] * scl) << 16);
    size_t off = ((size_t)(dd >> 4) * KT12 + (c8 >> 5)) * 512 +
                 (size_t)((((c8 >> 3) & 3) * 16 + (dd & 15)) * 8);
    *(uint4_*)(d + off) = pk;
}

// ---------------------------------------------------------------------------
// proj3_g: q/k/v projections, staged GEMM. 128x128 tile, 4 waves (64x64 each,
// 64 AGPR), K-step 32 (12 steps), A+B double-buffered via global_load_lds,
// one barrier per step. LDS cut to 32KB by aliasing the epilogue pw buffer
// into the staging region (dead after the final K-loop barrier) ->
// __launch_bounds__(256,4) for 4 blocks/CU of independent barrier domains.
// Grid 2304, 1-D: b = bid&31 -> batch XCD-local.
// ---------------------------------------------------------------------------
__global__ __launch_bounds__(256, 4) void proj3_g(
    const u16* __restrict__ rgb_sw, const u16* __restrict__ ms_sw,
    const u16* __restrict__ w_sw,
    u16* __restrict__ q_sw, u16* __restrict__ k_sw, u16* __restrict__ v_sw,
    const float* __restrict__ bq, const float* __restrict__ bk,
    const float* __restrict__ bv, float s0)
{
    // u16 layout: stA0 [0,4096) stA1 [4096,8192) stB0 [8192,12288)
    //             stB1 [12288,16384).  Epilogue pw (4x1216) aliases [0,4864).
    __shared__ __align__(16) u16 smem[16384];

    const int bid = blockIdx.x;
    const int b = bid & 31;
    const int rr = bid >> 5;              // [0,72)
    const int s = rr % 3, tile = rr / 3;  // tile in [0,24)
    const size_t TB = (size_t)NTOK * DIMC, WN = (size_t)DIMC * DIMC;
    const u16 *A, *B; u16* O; const float* bias;
    int ktd, bRow, r0, c0; float bsc = 1.f;
    if (s == 0) {
        A = rgb_sw + b * TB; B = w_sw; O = q_sw + b * TB; bias = bq;
        ktd = 12; bRow = 0; r0 = (tile & 7) * 128; c0 = (tile >> 3) * 128; bsc = s0;
    } else if (s == 1) {
        A = ms_sw + b * TB; B = w_sw + WN; O = k_sw + b * TB; bias = bk;
        ktd = 12; bRow = 0; r0 = (tile & 7) * 128; c0 = (tile >> 3) * 128;
    } else {
        A = w_sw + 2 * WN; B = ms_sw + b * TB; O = v_sw + b * TB; bias = bv;
        ktd = 32; bRow = 1; r0 = (tile % 3) * 128; c0 = (tile / 3) * 128;
    }

    const int t = threadIdx.x, w = t >> 6, lane = t & 63;
    const int l15 = lane & 15, quad = lane >> 4;
    const int wr = w >> 1, wc = w & 1;    // wave quadrant (rows, cols)
    const int rt0 = r0 >> 4, ct0 = c0 >> 4;

    f32x4 acc[4][4];
#pragma unroll
    for (int ai = 0; ai < 4; ++ai)
#pragma unroll
        for (int bj = 0; bj < 4; ++bj) acc[ai][bj] = (f32x4){0.f, 0.f, 0.f, 0.f};

    // prologue: stage K-step 0 into buffer 0 (wave w owns frags 2w, 2w+1)
    {
        const u16* As = A + ((size_t)(rt0 + 2 * w) * KT12) * 512 + (size_t)lane * 8;
        GLD_LDS16(As, smem + (2 * w) * 512);
        GLD_LDS16(As + KT12 * 512, smem + (2 * w + 1) * 512);
        const u16* Bs = B + ((size_t)(ct0 + 2 * w) * KT12) * 512 + (size_t)lane * 8;
        GLD_LDS16(Bs, smem + 8192 + (2 * w) * 512);
        GLD_LDS16(Bs + KT12 * 512, smem + 8192 + (2 * w + 1) * 512);
    }
    __syncthreads();

    for (int kt = 0; kt < 12; ++kt) {
        const int cur = kt & 1;
        if (kt < 11) {
            u16* dA = smem + (cur ^ 1) * 4096;
            u16* dB = smem + 8192 + (cur ^ 1) * 4096;
            const u16* As = A + ((size_t)(rt0 + 2 * w) * KT12 + kt + 1) * 512 + (size_t)lane * 8;
            GLD_LDS16(As, dA + (2 * w) * 512);
            GLD_LDS16(As + KT12 * 512, dA + (2 * w + 1) * 512);
            const u16* Bs = B + ((size_t)(ct0 + 2 * w) * KT12 + kt + 1) * 512 + (size_t)lane * 8;
            GLD_LDS16(Bs, dB + (2 * w) * 512);
            GLD_LDS16(Bs + KT12 * 512, dB + (2 * w + 1) * 512);
        }
        const u16* sA = smem + cur * 4096 + (size_t)(wr * 4) * 512 + (size_t)lane * 8;
        const u16* sB = smem + 8192 + cur * 4096 + (size_t)(wc * 4) * 512 + (size_t)lane * 8;
        short8 aF[4], bF[4];
#pragma unroll
        for (int ai = 0; ai < 4; ++ai) aF[ai] = *(const short8*)(sA + ai * 512);
#pragma unroll
        for (int bj = 0; bj < 4; ++bj) bF[bj] = *(const short8*)(sB + bj * 512);
        __builtin_amdgcn_s_setprio(1);
#pragma unroll
        for (int ai = 0; ai < 4; ++ai)
#pragma unroll
            for (int bj = 0; bj < 4; ++bj)
                acc[ai][bj] = MFMA16(aF[ai], bF[bj], acc[ai][bj], 0, 0, 0);
        __builtin_amdgcn_s_setprio(0);
        __syncthreads();  // drains vmcnt: next chunk landed; reads of cur done
    }
    // After the kt=11 barrier every wave's staging reads are complete ->
    // safe to alias pw onto the staging region.
    u16* pw = smem + w * 1216;

    // bias
    if (bRow) {
#pragma unroll
        for (int ai = 0; ai < 4; ++ai) {
            f32x4 bv4 = *(const f32x4*)(bias + r0 + wr * 64 + ai * 16 + quad * 4);
#pragma unroll
            for (int bj = 0; bj < 4; ++bj)
#pragma unroll
                for (int r = 0; r < 4; ++r) acc[ai][bj][r] += bv4[r];
        }
    } else {
#pragma unroll
        for (int bj = 0; bj < 4; ++bj) {
            float bc = bias[c0 + wc * 64 + bj * 16 + l15] * bsc;
#pragma unroll
            for (int ai = 0; ai < 4; ++ai)
#pragma unroll
                for (int r = 0; r < 4; ++r) acc[ai][bj][r] += bc;
        }
    }

    // epilogue: per-wave swizzled bf16 store (wave-private pw, no barriers)
#pragma unroll
    for (int ai = 0; ai < 4; ++ai) {
#pragma unroll
        for (int bj = 0; bj < 4; ++bj)
#pragma unroll
            for (int r = 0; r < 4; ++r)
                pw[(quad * 4 + r) * 76 + bj * 16 + l15] = f2bf(acc[ai][bj][r]);
        const int rt = rt0 + wr * 4 + ai;
        const int kb0 = (c0 + wc * 64) >> 5;
#pragma unroll
        for (int ktl = 0; ktl < 2; ++ktl) {
            uint4_ v = *(const uint4_*)(pw + l15 * 76 + ktl * 32 + quad * 8);
            *(uint4_*)(O + ((size_t)rt * ktd + kb0 + ktl) * 512 + (size_t)lane * 8) = v;
        }
    }
}

// ---------------------------------------------------------------------------
// projf_g: final projection, same staged-GEMM skeleton. 32KB LDS,
// __launch_bounds__(256,4). fp32 direct stores. grid 768.
// ---------------------------------------------------------------------------
__global__ __launch_bounds__(256, 4) void projf_g(
    const u16* __restrict__ wf_sw, const u16* __restrict__ osw,
    const float* __restrict__ bfp, float* __restrict__ out)
{
    __shared__ __align__(16) u16 smem[16384];
    const int bid = blockIdx.x;
    const int b = bid & 31, tile = bid >> 5;  // [0,24)
    const int r0 = (tile % 3) * 128, c0 = (tile / 3) * 128;
    const size_t TB = (size_t)NTOK * DIMC;

    const int t = threadIdx.x, w = t >> 6, lane = t & 63;
    const int l15 = lane & 15, quad = lane >> 4;
    const int wr = w >> 1, wc = w & 1;
    const int rt0 = r0 >> 4, ct0 = c0 >> 4;
    const u16* A = wf_sw;
    const u16* B = osw + (size_t)b * TB;

    f32x4 acc[4][4];
#pragma unroll
    for (int ai = 0; ai < 4; ++ai)
#pragma unroll
        for (int bj = 0; bj < 4; ++bj) acc[ai][bj] = (f32x4){0.f, 0.f, 0.f, 0.f};

    {
        const u16* As = A + ((size_t)(rt0 + 2 * w) * KT12) * 512 + (size_t)lane * 8;
        GLD_LDS16(As, smem + (2 * w) * 512);
        GLD_LDS16(As + KT12 * 512, smem + (2 * w + 1) * 512);
        const u16* Bs = B + ((size_t)(ct0 + 2 * w) * KT12) * 512 + (size_t)lane * 8;
        GLD_LDS16(Bs, smem + 8192 + (2 * w) * 512);
        GLD_LDS16(Bs + KT12 * 512, smem + 8192 + (2 * w + 1) * 512);
    }
    __syncthreads();

    for (int kt = 0; kt < 12; ++kt) {
        const int cur = kt & 1;
        if (kt < 11) {
            u16* dA = smem + (cur ^ 1) * 4096;
            u16* dB = smem + 8192 + (cur ^ 1) * 4096;
            const u16* As = A + ((size_t)(rt0 + 2 * w) * KT12 + kt + 1) * 512 + (size_t)lane * 8;
            GLD_LDS16(As, dA + (2 * w) * 512);
            GLD_LDS16(As + KT12 * 512, dA + (2 * w + 1) * 512);
            const u16* Bs = B + ((size_t)(ct0 + 2 * w) * KT12 + kt + 1) * 512 + (size_t)lane * 8;
            GLD_LDS16(Bs, dB + (2 * w) * 512);
            GLD_LDS16(Bs + KT12 * 512, dB + (2 * w + 1) * 512);
        }
        const u16* sA = smem + cur * 4096 + (size_t)(wr * 4) * 512 + (size_t)lane * 8;
        const u16* sB = smem + 8192 + cur * 4096 + (size_t)(wc * 4) * 512 + (size_t)lane * 8;
        short8 aF[4], bF[4];
#pragma unroll
        for (int ai = 0; ai < 4; ++ai) aF[ai] = *(const short8*)(sA + ai * 512);
#pragma unroll
        for (int bj = 0; bj < 4; ++bj) bF[bj] = *(const short8*)(sB + bj * 512);
        __builtin_amdgcn_s_setprio(1);
#pragma unroll
        for (int ai = 0; ai < 4; ++ai)
#pragma unroll
            for (int bj = 0; bj < 4; ++bj)
                acc[ai][bj] = MFMA16(aF[ai], bF[bj], acc[ai][bj], 0, 0, 0);
        __builtin_amdgcn_s_setprio(0);
        __syncthreads();
    }

    float* Ob = out + (size_t)b * DIMC * NTOK;
#pragma unroll
    for (int ai = 0; ai < 4; ++ai) {
        f32x4 bv4 = *(const f32x4*)(bfp + r0 + wr * 64 + ai * 16 + quad * 4);
#pragma unroll
        for (int bj = 0; bj < 4; ++bj) {
            const int col = c0 + wc * 64 + bj * 16 + l15;
#pragma unroll
            for (int r = 0; r < 4; ++r) {
                const int row = r0 + wr * 64 + ai * 16 + quad * 4 + r;
                Ob[(size_t)row * NTOK + col] = acc[ai][bj][r] + bv4[r];
            }
        }
    }
}

// ---------------------------------------------------------------------------
// attn_skew: flash attention, 128 q/block (8 waves x 16 q), 512 threads.
// Software-pipelined QK-skew: K triple-buffered, V double-buffered, all via
// global_load_lds. At iteration t the wave issues QK(t+1) MFMAs FIRST (into
// the spare S register pair), then runs softmax(t) + PV(t) while the matrix
// pipe retires QK(t+1) underneath the VALU work (MFMA and VALU are separate
// pipes; overlap needs no extra waves). Buffer hazards: kbuf[x] written at
// iter x-2 (barrier-drained), read iter x-1, rewritten iter x+1 -> always
// barrier-separated. One __syncthreads per tile. LDS 139KB, 1 block/CU.
// Static S registers via 2-unrolled loop + int rotation (no runtime-indexed
// register arrays).
// ---------------------------------------------------------------------------
__global__ __launch_bounds__(512, 2) void attn_skew(
    const u16* __restrict__ qsw, const u16* __restrict__ ksw,
    const u16* __restrict__ vsw, u16* __restrict__ osw)
{
    // u16 layout: kbuf0/1/2 [0,36864) vbuf0/1 [36864,61440)
    //             plds [61440,71168): 8 waves x 16 x 76
    __shared__ __align__(16) u16 smem[71168];

    const int bid = blockIdx.x;
    const int b = (bid & 7) * 4 + ((bid >> 3) & 3);  // same-batch blocks share XCD
    const int qb = bid >> 5;                         // [0,8): 128-q block index
    const int t = threadIdx.x, w = t >> 6, lane = t & 63;
    const int l15 = lane & 15, quad = lane >> 4;
    const int rt = qb * 8 + w;                       // global 16-q row-tile

    const size_t TB = (size_t)NTOK * DIMC;
    const u16* kb = ksw + (size_t)b * TB;
    const u16* vb = vsw + (size_t)b * TB;
    u16* pw = smem + 61440 + w * 1216;

    // Q fragments resident (pre-scaled by scale*log2e at projection)
    short8 qf[12];
    const u16* qp = qsw + (size_t)b * TB + (size_t)rt * (KT12 * 512) + (size_t)lane * 8;
#pragma unroll
    for (int dk = 0; dk < 12; ++dk) qf[dk] = *(const short8*)(qp + dk * 512);

    f32x4 Oa[24];
#pragma unroll
    for (int i = 0; i < 24; ++i) Oa[i] = (f32x4){0.f, 0.f, 0.f, 0.f};
    float m_run[4], l_run[4];
#pragma unroll
    for (int r = 0; r < 4; ++r) { m_run[r] = -1e30f; l_run[r] = 0.f; }

    const int i0 = w * 3;  // this wave's 3 fragment indices (of 24)

    // prologue: DMA K(0)->kbuf0, K(1)->kbuf1, V(0)->vbuf0
#pragma unroll
    for (int j = 0; j < 3; ++j) {
        int idx = i0 + j;
        GLD_LDS16(kb + (size_t)idx * 512 + lane * 8, smem + idx * 512);
        GLD_LDS16(kb + (size_t)(24 + idx) * 512 + lane * 8, smem + 12288 + idx * 512);
        GLD_LDS16(vb + (size_t)(idx * 32) * 512 + lane * 8, smem + 36864 + idx * 512);
    }
    __syncthreads();

    f32x4 s0[2], s1[2];
    // QK(0) from kbuf0 -> s0
    {
        s0[0] = (f32x4){0.f, 0.f, 0.f, 0.f};
        s0[1] = (f32x4){0.f, 0.f, 0.f, 0.f};
        const u16* kfb = smem + (size_t)lane * 8;
        __builtin_amdgcn_s_setprio(1);
#pragma unroll
        for (int dk = 0; dk < 12; ++dk) {
            short8 k0 = *(const short8*)(kfb + dk * 512);
            short8 k1 = *(const short8*)(kfb + (12 + dk) * 512);
            s0[0] = MFMA16(qf[dk], k0, s0[0], 0, 0, 0);
            s0[1] = MFMA16(qf[dk], k1, s0[1], 0, 0, 0);
        }
        __builtin_amdgcn_s_setprio(0);
    }

    auto body = [&](int mt, f32x4 (&SC)[2], f32x4 (&SP)[2], int qkb, int dmb) {
        // DMA K(mt+2) -> kbuf[dmb], V(mt+1) -> vbuf[(mt+1)&1]
        if (mt < 30) {
            u16* kd = smem + dmb * 12288;
            const u16* ks = kb + (size_t)(24 * (mt + 2)) * 512 + (size_t)lane * 8;
#pragma unroll
            for (int j = 0; j < 3; ++j) {
                int idx = i0 + j;
                GLD_LDS16(ks + (size_t)idx * 512, kd + idx * 512);
            }
        }
        if (mt < 31) {
            u16* vd = smem + 36864 + ((mt + 1) & 1) * 12288;
            const u16* vs = vb + (size_t)(mt + 1) * 512 + (size_t)lane * 8;
#pragma unroll
            for (int j = 0; j < 3; ++j) {
                int idx = i0 + j;
                GLD_LDS16(vs + (size_t)(idx * 32) * 512, vd + idx * 512);
            }
            // QK(mt+1) from kbuf[qkb] -> SP (retires under softmax/PV below)
            SP[0] = (f32x4){0.f, 0.f, 0.f, 0.f};
            SP[1] = (f32x4){0.f, 0.f, 0.f, 0.f};
            const u16* kfb = smem + qkb * 12288 + (size_t)lane * 8;
            __builtin_amdgcn_s_setprio(1);
#pragma unroll
            for (int dk = 0; dk < 12; ++dk) {
                short8 k0 = *(const short8*)(kfb + dk * 512);
                short8 k1 = *(const short8*)(kfb + (12 + dk) * 512);
                SP[0] = MFMA16(qf[dk], k0, SP[0], 0, 0, 0);
                SP[1] = MFMA16(qf[dk], k1, SP[1], 0, 0, 0);
            }
            __builtin_amdgcn_s_setprio(0);
        }

        // ---- online softmax on SC (tile mt; log2-domain, deferred-max) ----
        float mx4[4];
#pragma unroll
        for (int r = 0; r < 4; ++r) {
            float mx = fmaxf(SC[0][r], SC[1][r]);
            mx = fmaxf(mx, __shfl_xor(mx, 1));
            mx = fmaxf(mx, __shfl_xor(mx, 2));
            mx = fmaxf(mx, __shfl_xor(mx, 4));
            mx = fmaxf(mx, __shfl_xor(mx, 8));
            mx4[r] = mx;
        }
        int grow = (mx4[0] > m_run[0] + 8.f) | (mx4[1] > m_run[1] + 8.f) |
                   (mx4[2] > m_run[2] + 8.f) | (mx4[3] > m_run[3] + 8.f);
        if (__any(grow)) {
            float alpha[4];
#pragma unroll
            for (int r = 0; r < 4; ++r) {
                float mn = fmaxf(m_run[r], mx4[r]);
                alpha[r] = exp2f(m_run[r] - mn);
                m_run[r] = mn;
                l_run[r] *= alpha[r];
            }
#pragma unroll
            for (int ci = 0; ci < 24; ++ci)
#pragma unroll
                for (int r = 0; r < 4; ++r) Oa[ci][r] *= alpha[r];
        }
#pragma unroll
        for (int r = 0; r < 4; ++r) {
            float ls = 0.f;
#pragma unroll
            for (int mc = 0; mc < 2; ++mc) {
                float p = exp2f(SC[mc][r] - m_run[r]);
                u16 pb = f2bf(p);
                pw[(quad * 4 + r) * 76 + mc * 16 + l15] = pb;
                ls += bf2f(pb);  // denominator from rounded P -> exact normalization
            }
            ls += __shfl_xor(ls, 1);
            ls += __shfl_xor(ls, 2);
            ls += __shfl_xor(ls, 4);
            ls += __shfl_xor(ls, 8);
            l_run[r] += ls;
        }

        // ---- PV(mt): P (wave-private LDS) x V (LDS) ----
        short8 pa = *(const short8*)(pw + l15 * 76 + quad * 8);
        const u16* vfb = smem + 36864 + (mt & 1) * 12288 + (size_t)lane * 8;
        __builtin_amdgcn_s_setprio(1);
#pragma unroll
        for (int ci = 0; ci < 24; ++ci) {
            short8 vf = *(const short8*)(vfb + ci * 512);
            Oa[ci] = MFMA16(pa, vf, Oa[ci], 0, 0, 0);
        }
        __builtin_amdgcn_s_setprio(0);

        __syncthreads();  // drains vmcnt: DMAs landed; all reads of mt done
    };

    // buffer-index rotation: for iter t, QK reads (t+1)%3, DMA writes (t+2)%3
    int b0 = 0, b1 = 1, b2 = 2;
    for (int tp = 0; tp < 16; ++tp) {
        const int mt = 2 * tp;
        body(mt, s0, s1, b1, b2);
        body(mt + 1, s1, s0, b2, b0);
        int tmp = b0; b0 = b2; b2 = b1; b1 = tmp;
    }

    // ---- epilogue: normalize + wave-private transpose via pw + store ----
    float rl[4];
#pragma unroll
    for (int r = 0; r < 4; ++r) rl[r] = 1.f / l_run[r];
    u16* od = osw + (size_t)b * TB;
#pragma unroll
    for (int ch = 0; ch < 6; ++ch) {
#pragma unroll
        for (int cc = 0; cc < 4; ++cc)
#pragma unroll
            for (int r = 0; r < 4; ++r)
                pw[(quad * 4 + r) * 76 + cc * 16 + l15] = f2bf(Oa[ch * 4 + cc][r] * rl[r]);
#pragma unroll
        for (int ktl = 0; ktl < 2; ++ktl) {
            uint4_ vv = *(const uint4_*)(pw + l15 * 76 + ktl * 32 + quad * 8);
            size_t dst = ((size_t)rt * KT12 + ch * 2 + ktl) * 512 + (size_t)lane * 8;
            *(uint4_*)(od + dst) = vv;
        }
    }
}

extern "C" void kernel_launch(void* const* d_in, const int* in_sizes, int n_in,
                              void* d_out, int out_size, void* d_ws, size_t ws_size,
                              hipStream_t stream) {
    const float* rgb = (const float*)d_in[0];
    const float* ms  = (const float*)d_in[1];
    const float* Wq  = (const float*)d_in[2];
    const float* bq  = (const float*)d_in[3];
    const float* Wk  = (const float*)d_in[4];
    const float* bk  = (const float*)d_in[5];
    const float* Wv  = (const float*)d_in[6];
    const float* bv  = (const float*)d_in[7];
    const float* Wf  = (const float*)d_in[8];
    const float* bf_ = (const float*)d_in[9];
    float* outp = (float*)d_out;

    const float SC2 = 0.05103103630798288f * 1.4426950408889634f;  // scale*log2e

    const size_t TN = (size_t)BATCH * NTOK * DIMC;  // 12.58M elems
    const size_t WN = (size_t)DIMC * DIMC;          // 147456
    u16* rgb_sw = (u16*)d_ws;         // swizzle R=n K=c
    u16* ms_sw  = rgb_sw + TN;
    u16* q_sw   = ms_sw + TN;         // R=n K=d (pre-scaled)
    u16* k_sw   = q_sw + TN;          // R=m K=d
    u16* v_sw   = k_sw + TN;          // R=c K=m (KT=32)
    u16* o_sw   = v_sw + TN;          // R=n K=c
    u16* w_sw   = o_sw + TN;          // Wq,Wk,Wv,Wf swizzled concat
    // total ws: 6*25.2MB + 1.2MB = 152 MB

    wcvt_sw<<<dim3(72, 4), 256, 0, stream>>>(Wq, Wk, Wv, Wf, w_sw, SC2);
    transpose_sw<<<dim3(16, 6, 2 * BATCH), 256, 0, stream>>>(rgb, rgb_sw, ms, ms_sw);

    proj3_g<<<dim3(2304), 256, 0, stream>>>(
        rgb_sw, ms_sw, w_sw, q_sw, k_sw, v_sw, bq, bk, bv, SC2);

    attn_skew<<<dim3(256), 512, 0, stream>>>(q_sw, k_sw, v_sw, o_sw);

    projf_g<<<dim3(768), 256, 0, stream>>>(w_sw + 3 * WN, o_sw, bf_, outp);
}

// Round 6
// 320.152 us; speedup vs baseline: 1.8061x; 1.0301x over previous
//
#include <hip/hip_runtime.h>

#define DIMC 384
#define NTOK 1024
#define BATCH 32
#define KT12 12

using short8 = __attribute__((ext_vector_type(8))) short;
using f32x4  = __attribute__((ext_vector_type(4))) float;
using uint4_ = __attribute__((ext_vector_type(4))) unsigned int;
typedef unsigned short u16;

#define MFMA16 __builtin_amdgcn_mfma_f32_16x16x32_bf16

// async global->LDS, 16B/lane. LDS dest = wave-uniform base + lane*16.
#define GLD_LDS16(gp, lp)                                                     \
    __builtin_amdgcn_global_load_lds(                                         \
        (const __attribute__((address_space(1))) void*)(gp),                  \
        (__attribute__((address_space(3))) void*)(lp), 16, 0, 0)

__device__ __forceinline__ u16 f2bf(float f) {
    unsigned int u = __builtin_bit_cast(unsigned int, f);
    u += 0x7FFFu + ((u >> 16) & 1u);
    return (u16)(u >> 16);
}
__device__ __forceinline__ float bf2f(u16 h) {
    unsigned int u = ((unsigned int)h) << 16;
    return __builtin_bit_cast(float, u);
}

// Unified fragment-contiguous swizzle for matrix M[R][K] (K = contraction):
//   flat = ((r>>4)*KT + (k>>5))*512 + (((k>>3)&3)*16 + (r&15))*8 + (k&7)
// One MFMA A/B fragment (rt, kt) = 1 KB contiguous at ((rt*KT+kt)*64+lane)*8.

// ---------------------------------------------------------------------------
// transpose_sw: X (b, c, n) fp32 -> X_sw (b, swizzle R=n K=c) bf16.
// grid (16, 6, 2*BATCH): z<32 -> rgb, z>=32 -> ms (one launch for both).
// ---------------------------------------------------------------------------
__global__ __launch_bounds__(256) void transpose_sw(
    const float* __restrict__ X0, u16* __restrict__ X0sw,
    const float* __restrict__ X1, u16* __restrict__ X1sw)
{
    __shared__ float tl[64 * 65];
    const int z = blockIdx.z;
    const float* X = (z < BATCH) ? X0 : X1;
    u16* Xsw = (z < BATCH) ? X0sw : X1sw;
    const int b = z & 31, n0 = blockIdx.x * 64, c0 = blockIdx.y * 64;
    const int t = threadIdx.x;

#pragma unroll
    for (int p = 0; p < 4; ++p) {
        int idx = p * 256 + t;
        int c = idx >> 4, n4 = (idx & 15) * 4;
        f32x4 v = *(const f32x4*)(X + ((size_t)b * DIMC + c0 + c) * NTOK + n0 + n4);
#pragma unroll
        for (int i = 0; i < 4; ++i) tl[c * 65 + n4 + i] = v[i];
    }
    __syncthreads();
    u16* dstb = Xsw + (size_t)b * NTOK * DIMC;
#pragma unroll
    for (int p = 0; p < 2; ++p) {
        int g = p * 256 + t;  // [3:0]=n15 [5:4]=quad [6]=ktl [8:7]=rg
        int n15 = g & 15, quad = (g >> 4) & 3, ktl = (g >> 6) & 1, rg = g >> 7;
        int c8 = ktl * 32 + quad * 8;
        int nl = rg * 16 + n15;
        uint4_ pk;
#pragma unroll
        for (int i = 0; i < 4; ++i) {
            u16 lo = f2bf(tl[(c8 + 2 * i) * 65 + nl]);
            u16 hi = f2bf(tl[(c8 + 2 * i + 1) * 65 + nl]);
            pk[i] = (unsigned)lo | ((unsigned)hi << 16);
        }
        size_t dst = (((size_t)(n0 >> 4) + rg) * KT12 + (c0 >> 5) + ktl) * 512 + (size_t)(g & 63) * 8;
        *(uint4_*)(dstb + dst) = pk;
    }
}

// ---------------------------------------------------------------------------
// wcvt_sw: 4 weight matrices (384x384 fp32 [d][c]) -> swizzle bf16 (R=d, K=c),
// concatenated. Matrix 0 (Wq) pre-scaled by scale*log2e. grid (72,4), 256 thr.
// ---------------------------------------------------------------------------
__global__ __launch_bounds__(256) void wcvt_sw(
    const float* __restrict__ w0, const float* __restrict__ w1,
    const float* __restrict__ w2, const float* __restrict__ w3,
    u16* __restrict__ dst, float s0)
{
    const float* srcs[4] = {w0, w1, w2, w3};
    const float* s = srcs[blockIdx.y];
    float scl = (blockIdx.y == 0) ? s0 : 1.0f;
    u16* d = dst + (size_t)blockIdx.y * DIMC * DIMC;
    int e0 = (blockIdx.x * 256 + threadIdx.x) * 8;
    int dd = e0 / DIMC, c8 = e0 % DIMC;
    f32x4 a = *(const f32x4*)(s + e0);
    f32x4 b2 = *(const f32x4*)(s + e0 + 4);
    uint4_ pk;
    pk[0] = (unsigned)f2bf(a[0] * scl) | ((unsigned)f2bf(a[1] * scl) << 16);
    pk[1] = (unsigned)f2bf(a[2] * scl) | ((unsigned)f2bf(a[3] * scl) << 16);
    pk[2] = (unsigned)f2bf(b2[0] * scl) | ((unsigned)f2bf(b2[1] * scl) << 16);
    pk[3] = (unsigned)f2bf(b2[2] * scl) | ((unsigned)f2bf(b2[3] * scl) << 16);
    size_t off = ((size_t)(dd >> 4) * KT12 + (c8 >> 5)) * 512 +
                 (size_t)((((c8 >> 3) & 3) * 16 + (dd & 15)) * 8);
    *(uint4_*)(d + off) = pk;
}

// ---------------------------------------------------------------------------
// proj3_g: q/k/v projections, staged GEMM with T4 counted-vmcnt pipeline.
// 128x128 tile, 4 waves (64x64 each, 64 AGPR), K-step 32 (12 steps).
// TRIPLE-buffered A/B staging (48KB LDS, 3 blocks/CU): DMA for step kt+2
// issued right after the barrier; the pre-barrier wait is s_waitcnt vmcnt(4)
// (only the newest 4 loads — step kt+1's — may remain in flight), NOT the
// full vmcnt(0) drain __syncthreads emits. Prefetch window = 2 compute
// phases. Hazards: WAR — buf (kt+2)%3 last read at iter kt-1, reads complete
// before each wave's iter-kt barrier arrival -> post-barrier issue safe.
// RAW — vmcnt(4) guarantees step kt's 4 loads landed before the barrier.
// Tail iters drain with vmcnt(0). Grid 2304, b = bid&31 -> batch XCD-local.
// ---------------------------------------------------------------------------
__global__ __launch_bounds__(256, 3) void proj3_g(
    const u16* __restrict__ rgb_sw, const u16* __restrict__ ms_sw,
    const u16* __restrict__ w_sw,
    u16* __restrict__ q_sw, u16* __restrict__ k_sw, u16* __restrict__ v_sw,
    const float* __restrict__ bq, const float* __restrict__ bk,
    const float* __restrict__ bv, float s0)
{
    // u16 layout: stA0/1/2 [0,12288)  stB0/1/2 [12288,24576)
    // Epilogue pw (4x1216 = [0,4864)) aliases stA0/stA1: both dead and
    // vmcnt-drained after the final (kt=11) barrier.
    __shared__ __align__(16) u16 smem[24576];

    const int bid = blockIdx.x;
    const int b = bid & 31;
    const int rr = bid >> 5;              // [0,72)
    const int s = rr % 3, tile = rr / 3;  // tile in [0,24)
    const size_t TB = (size_t)NTOK * DIMC, WN = (size_t)DIMC * DIMC;
    const u16 *A, *B; u16* O; const float* bias;
    int ktd, bRow, r0, c0; float bsc = 1.f;
    if (s == 0) {
        A = rgb_sw + b * TB; B = w_sw; O = q_sw + b * TB; bias = bq;
        ktd = 12; bRow = 0; r0 = (tile & 7) * 128; c0 = (tile >> 3) * 128; bsc = s0;
    } else if (s == 1) {
        A = ms_sw + b * TB; B = w_sw + WN; O = k_sw + b * TB; bias = bk;
        ktd = 12; bRow = 0; r0 = (tile & 7) * 128; c0 = (tile >> 3) * 128;
    } else {
        A = w_sw + 2 * WN; B = ms_sw + b * TB; O = v_sw + b * TB; bias = bv;
        ktd = 32; bRow = 1; r0 = (tile % 3) * 128; c0 = (tile / 3) * 128;
    }

    const int t = threadIdx.x, w = t >> 6, lane = t & 63;
    const int l15 = lane & 15, quad = lane >> 4;
    const int wr = w >> 1, wc = w & 1;    // wave quadrant (rows, cols)
    const int rt0 = r0 >> 4, ct0 = c0 >> 4;

    f32x4 acc[4][4];
#pragma unroll
    for (int ai = 0; ai < 4; ++ai)
#pragma unroll
        for (int bj = 0; bj < 4; ++bj) acc[ai][bj] = (f32x4){0.f, 0.f, 0.f, 0.f};

    const u16* Aw = A + ((size_t)(rt0 + 2 * w) * KT12) * 512 + (size_t)lane * 8;
    const u16* Bw = B + ((size_t)(ct0 + 2 * w) * KT12) * 512 + (size_t)lane * 8;

    // prologue: issue DMA for steps 0 (buf0) and 1 (buf1); no barrier yet
#pragma unroll
    for (int kn = 0; kn < 2; ++kn) {
        u16* dA = smem + kn * 4096;
        u16* dB = smem + 12288 + kn * 4096;
        GLD_LDS16(Aw + (size_t)kn * 512, dA + (2 * w) * 512);
        GLD_LDS16(Aw + (size_t)(KT12 + kn) * 512, dA + (2 * w + 1) * 512);
        GLD_LDS16(Bw + (size_t)kn * 512, dB + (2 * w) * 512);
        GLD_LDS16(Bw + (size_t)(KT12 + kn) * 512, dB + (2 * w + 1) * 512);
    }

#pragma unroll
    for (int kt = 0; kt < 12; ++kt) {
        // counted wait: step kt's 4 loads (oldest) complete; step kt+1's may fly
        if (kt < 11) {
            asm volatile("s_waitcnt vmcnt(4)" ::: "memory");
        } else {
            asm volatile("s_waitcnt vmcnt(0)" ::: "memory");
        }
        __builtin_amdgcn_s_barrier();
        __builtin_amdgcn_sched_barrier(0);

        // issue DMA for step kt+2 into buf (kt+2)%3 (post-barrier: WAR-safe)
        if (kt < 10) {
            const int kn = kt + 2, bf = kn % 3;
            u16* dA = smem + bf * 4096;
            u16* dB = smem + 12288 + bf * 4096;
            GLD_LDS16(Aw + (size_t)kn * 512, dA + (2 * w) * 512);
            GLD_LDS16(Aw + (size_t)(KT12 + kn) * 512, dA + (2 * w + 1) * 512);
            GLD_LDS16(Bw + (size_t)kn * 512, dB + (2 * w) * 512);
            GLD_LDS16(Bw + (size_t)(KT12 + kn) * 512, dB + (2 * w + 1) * 512);
        }

        const int cb = kt % 3;
        const u16* sA = smem + cb * 4096 + (size_t)(wr * 4) * 512 + (size_t)lane * 8;
        const u16* sB = smem + 12288 + cb * 4096 + (size_t)(wc * 4) * 512 + (size_t)lane * 8;
        short8 aF[4], bF[4];
#pragma unroll
        for (int ai = 0; ai < 4; ++ai) aF[ai] = *(const short8*)(sA + ai * 512);
#pragma unroll
        for (int bj = 0; bj < 4; ++bj) bF[bj] = *(const short8*)(sB + bj * 512);
        __builtin_amdgcn_s_setprio(1);
#pragma unroll
        for (int ai = 0; ai < 4; ++ai)
#pragma unroll
            for (int bj = 0; bj < 4; ++bj)
                acc[ai][bj] = MFMA16(aF[ai], bF[bj], acc[ai][bj], 0, 0, 0);
        __builtin_amdgcn_s_setprio(0);
    }
    // All buffers read-complete and vmcnt-drained; alias pw onto stA0/stA1.
    u16* pw = smem + w * 1216;

    // bias
    if (bRow) {
#pragma unroll
        for (int ai = 0; ai < 4; ++ai) {
            f32x4 bv4 = *(const f32x4*)(bias + r0 + wr * 64 + ai * 16 + quad * 4);
#pragma unroll
            for (int bj = 0; bj < 4; ++bj)
#pragma unroll
                for (int r = 0; r < 4; ++r) acc[ai][bj][r] += bv4[r];
        }
    } else {
#pragma unroll
        for (int bj = 0; bj < 4; ++bj) {
            float bc = bias[c0 + wc * 64 + bj * 16 + l15] * bsc;
#pragma unroll
            for (int ai = 0; ai < 4; ++ai)
#pragma unroll
                for (int r = 0; r < 4; ++r) acc[ai][bj][r] += bc;
        }
    }

    // epilogue: per-wave swizzled bf16 store (wave-private pw, no barriers)
#pragma unroll
    for (int ai = 0; ai < 4; ++ai) {
#pragma unroll
        for (int bj = 0; bj < 4; ++bj)
#pragma unroll
            for (int r = 0; r < 4; ++r)
                pw[(quad * 4 + r) * 76 + bj * 16 + l15] = f2bf(acc[ai][bj][r]);
        const int rt = rt0 + wr * 4 + ai;
        const int kb0 = (c0 + wc * 64) >> 5;
#pragma unroll
        for (int ktl = 0; ktl < 2; ++ktl) {
            uint4_ v = *(const uint4_*)(pw + l15 * 76 + ktl * 32 + quad * 8);
            *(uint4_*)(O + ((size_t)rt * ktd + kb0 + ktl) * 512 + (size_t)lane * 8) = v;
        }
    }
}

// ---------------------------------------------------------------------------
// projf_g: final projection, same T4 counted-vmcnt skeleton. fp32 direct
// stores. grid 768.
// ---------------------------------------------------------------------------
__global__ __launch_bounds__(256, 3) void projf_g(
    const u16* __restrict__ wf_sw, const u16* __restrict__ osw,
    const float* __restrict__ bfp, float* __restrict__ out)
{
    __shared__ __align__(16) u16 smem[24576];
    const int bid = blockIdx.x;
    const int b = bid & 31, tile = bid >> 5;  // [0,24)
    const int r0 = (tile % 3) * 128, c0 = (tile / 3) * 128;
    const size_t TB = (size_t)NTOK * DIMC;

    const int t = threadIdx.x, w = t >> 6, lane = t & 63;
    const int l15 = lane & 15, quad = lane >> 4;
    const int wr = w >> 1, wc = w & 1;
    const int rt0 = r0 >> 4, ct0 = c0 >> 4;
    const u16* A = wf_sw;
    const u16* B = osw + (size_t)b * TB;

    f32x4 acc[4][4];
#pragma unroll
    for (int ai = 0; ai < 4; ++ai)
#pragma unroll
        for (int bj = 0; bj < 4; ++bj) acc[ai][bj] = (f32x4){0.f, 0.f, 0.f, 0.f};

    const u16* Aw = A + ((size_t)(rt0 + 2 * w) * KT12) * 512 + (size_t)lane * 8;
    const u16* Bw = B + ((size_t)(ct0 + 2 * w) * KT12) * 512 + (size_t)lane * 8;

#pragma unroll
    for (int kn = 0; kn < 2; ++kn) {
        u16* dA = smem + kn * 4096;
        u16* dB = smem + 12288 + kn * 4096;
        GLD_LDS16(Aw + (size_t)kn * 512, dA + (2 * w) * 512);
        GLD_LDS16(Aw + (size_t)(KT12 + kn) * 512, dA + (2 * w + 1) * 512);
        GLD_LDS16(Bw + (size_t)kn * 512, dB + (2 * w) * 512);
        GLD_LDS16(Bw + (size_t)(KT12 + kn) * 512, dB + (2 * w + 1) * 512);
    }

#pragma unroll
    for (int kt = 0; kt < 12; ++kt) {
        if (kt < 11) {
            asm volatile("s_waitcnt vmcnt(4)" ::: "memory");
        } else {
            asm volatile("s_waitcnt vmcnt(0)" ::: "memory");
        }
        __builtin_amdgcn_s_barrier();
        __builtin_amdgcn_sched_barrier(0);

        if (kt < 10) {
            const int kn = kt + 2, bf = kn % 3;
            u16* dA = smem + bf * 4096;
            u16* dB = smem + 12288 + bf * 4096;
            GLD_LDS16(Aw + (size_t)kn * 512, dA + (2 * w) * 512);
            GLD_LDS16(Aw + (size_t)(KT12 + kn) * 512, dA + (2 * w + 1) * 512);
            GLD_LDS16(Bw + (size_t)kn * 512, dB + (2 * w) * 512);
            GLD_LDS16(Bw + (size_t)(KT12 + kn) * 512, dB + (2 * w + 1) * 512);
        }

        const int cb = kt % 3;
        const u16* sA = smem + cb * 4096 + (size_t)(wr * 4) * 512 + (size_t)lane * 8;
        const u16* sB = smem + 12288 + cb * 4096 + (size_t)(wc * 4) * 512 + (size_t)lane * 8;
        short8 aF[4], bF[4];
#pragma unroll
        for (int ai = 0; ai < 4; ++ai) aF[ai] = *(const short8*)(sA + ai * 512);
#pragma unroll
        for (int bj = 0; bj < 4; ++bj) bF[bj] = *(const short8*)(sB + bj * 512);
        __builtin_amdgcn_s_setprio(1);
#pragma unroll
        for (int ai = 0; ai < 4; ++ai)
#pragma unroll
            for (int bj = 0; bj < 4; ++bj)
                acc[ai][bj] = MFMA16(aF[ai], bF[bj], acc[ai][bj], 0, 0, 0);
        __builtin_amdgcn_s_setprio(0);
    }

    float* Ob = out + (size_t)b * DIMC * NTOK;
#pragma unroll
    for (int ai = 0; ai < 4; ++ai) {
        f32x4 bv4 = *(const f32x4*)(bfp + r0 + wr * 64 + ai * 16 + quad * 4);
#pragma unroll
        for (int bj = 0; bj < 4; ++bj) {
            const int col = c0 + wc * 64 + bj * 16 + l15;
#pragma unroll
            for (int r = 0; r < 4; ++r) {
                const int row = r0 + wr * 64 + ai * 16 + quad * 4 + r;
                Ob[(size_t)row * NTOK + col] = acc[ai][bj][r] + bv4[r];
            }
        }
    }
}

// ---------------------------------------------------------------------------
// attn_lds: flash attention, 128 q/block (8 waves x 16 q), 512 threads.
// (Round-3 proven version, 104 us.) BOTH K and V double-buffered in LDS via
// async global_load_lds: 32-key tiles, 32 iterations, ONE barrier per tile.
// DMA for tile t+1 (6 frags/wave) issued right after the tile-t barrier.
// LDS 115KB -> 1 block/CU, 8 waves/CU. Grid 256; bid mapping keeps all 8
// blocks of a batch on one XCD (measured FETCH 37MB, conflicts 0).
// ---------------------------------------------------------------------------
__global__ __launch_bounds__(512, 2) void attn_lds(
    const u16* __restrict__ qsw, const u16* __restrict__ ksw,
    const u16* __restrict__ vsw, u16* __restrict__ osw)
{
    // u16 layout: kbuf0 [0,12288) kbuf1 [12288,24576)
    //             vbuf0 [24576,36864) vbuf1 [36864,49152)
    //             plds  [49152,58880): 8 waves x 16 rows x 76
    __shared__ __align__(16) u16 smem[58880];

    const int bid = blockIdx.x;
    const int b = (bid & 7) * 4 + ((bid >> 3) & 3);  // same-batch blocks share XCD
    const int qb = bid >> 5;                         // [0,8): 128-q block index
    const int t = threadIdx.x, w = t >> 6, lane = t & 63;
    const int l15 = lane & 15, quad = lane >> 4;
    const int rt = qb * 8 + w;                       // global 16-q row-tile

    const size_t TB = (size_t)NTOK * DIMC;
    const u16* kb = ksw + (size_t)b * TB;
    const u16* vb = vsw + (size_t)b * TB;
    u16* pw = smem + 49152 + w * 1216;

    // Q fragments resident (pre-scaled by scale*log2e at projection)
    short8 qf[12];
    const u16* qp = qsw + (size_t)b * TB + (size_t)rt * (KT12 * 512) + (size_t)lane * 8;
#pragma unroll
    for (int dk = 0; dk < 12; ++dk) qf[dk] = *(const short8*)(qp + dk * 512);

    f32x4 Oa[24];
#pragma unroll
    for (int i = 0; i < 24; ++i) Oa[i] = (f32x4){0.f, 0.f, 0.f, 0.f};
    float m_run[4], l_run[4];
#pragma unroll
    for (int r = 0; r < 4; ++r) { m_run[r] = -1e30f; l_run[r] = 0.f; }

    const int i0 = w * 3;  // this wave's 3 fragment indices (of 24)

    // prologue: DMA tile 0 into buffer 0
#pragma unroll
    for (int j = 0; j < 3; ++j) {
        int idx = i0 + j;
        GLD_LDS16(kb + (size_t)idx * 512 + lane * 8, smem + idx * 512);
        GLD_LDS16(vb + (size_t)(idx * 32) * 512 + lane * 8, smem + 24576 + idx * 512);
    }
    __syncthreads();

    for (int mt = 0; mt < 32; ++mt) {
        const int cur = mt & 1;
        u16* kcur = smem + cur * 12288;
        u16* vcur = smem + 24576 + cur * 12288;

        // issue DMA for tile mt+1 into the other buffer (lands during compute)
        if (mt < 31) {
            u16* knxt = smem + (cur ^ 1) * 12288;
            u16* vnxt = smem + 24576 + (cur ^ 1) * 12288;
#pragma unroll
            for (int j = 0; j < 3; ++j) {
                int idx = i0 + j;
                GLD_LDS16(kb + (size_t)(24 * (mt + 1) + idx) * 512 + lane * 8,
                          knxt + idx * 512);
                GLD_LDS16(vb + (size_t)(idx * 32 + mt + 1) * 512 + lane * 8,
                          vnxt + idx * 512);
            }
        }

        // ---- QK: S[16 q][32 keys] from LDS K frags ----
        f32x4 s[2];
        s[0] = (f32x4){0.f, 0.f, 0.f, 0.f};
        s[1] = (f32x4){0.f, 0.f, 0.f, 0.f};
        const u16* kfb = kcur + (size_t)lane * 8;
        __builtin_amdgcn_s_setprio(1);
#pragma unroll
        for (int dk = 0; dk < 12; ++dk) {
            short8 k0 = *(const short8*)(kfb + dk * 512);
            short8 k1 = *(const short8*)(kfb + (12 + dk) * 512);
            s[0] = MFMA16(qf[dk], k0, s[0], 0, 0, 0);
            s[1] = MFMA16(qf[dk], k1, s[1], 0, 0, 0);
        }
        __builtin_amdgcn_s_setprio(0);

        // ---- online softmax (log2-domain, deferred-max THR=8) ----
        float mx4[4];
#pragma unroll
        for (int r = 0; r < 4; ++r) {
            float mx = fmaxf(s[0][r], s[1][r]);
            mx = fmaxf(mx, __shfl_xor(mx, 1));
            mx = fmaxf(mx, __shfl_xor(mx, 2));
            mx = fmaxf(mx, __shfl_xor(mx, 4));
            mx = fmaxf(mx, __shfl_xor(mx, 8));
            mx4[r] = mx;
        }
        int grow = (mx4[0] > m_run[0] + 8.f) | (mx4[1] > m_run[1] + 8.f) |
                   (mx4[2] > m_run[2] + 8.f) | (mx4[3] > m_run[3] + 8.f);
        if (__any(grow)) {
            float alpha[4];
#pragma unroll
            for (int r = 0; r < 4; ++r) {
                float mn = fmaxf(m_run[r], mx4[r]);
                alpha[r] = exp2f(m_run[r] - mn);
                m_run[r] = mn;
                l_run[r] *= alpha[r];
            }
#pragma unroll
            for (int ci = 0; ci < 24; ++ci)
#pragma unroll
                for (int r = 0; r < 4; ++r) Oa[ci][r] *= alpha[r];
        }
#pragma unroll
        for (int r = 0; r < 4; ++r) {
            float ls = 0.f;
#pragma unroll
            for (int mc = 0; mc < 2; ++mc) {
                float p = exp2f(s[mc][r] - m_run[r]);
                u16 pb = f2bf(p);
                pw[(quad * 4 + r) * 76 + mc * 16 + l15] = pb;
                ls += bf2f(pb);  // denominator from rounded P -> exact normalization
            }
            ls += __shfl_xor(ls, 1);
            ls += __shfl_xor(ls, 2);
            ls += __shfl_xor(ls, 4);
            ls += __shfl_xor(ls, 8);
            l_run[r] += ls;
        }

        // ---- PV: P (wave-private LDS) x V (LDS), 24 independent chains ----
        short8 pa = *(const short8*)(pw + l15 * 76 + quad * 8);
        const u16* vfb = vcur + (size_t)lane * 8;
        __builtin_amdgcn_s_setprio(1);
#pragma unroll
        for (int ci = 0; ci < 24; ++ci) {
            short8 vf = *(const short8*)(vfb + ci * 512);
            Oa[ci] = MFMA16(pa, vf, Oa[ci], 0, 0, 0);
        }
        __builtin_amdgcn_s_setprio(0);

        __syncthreads();  // drains vmcnt: tile mt+1 landed; all reads of mt done
    }

    // ---- epilogue: normalize + wave-private transpose via pw + store ----
    float rl[4];
#pragma unroll
    for (int r = 0; r < 4; ++r) rl[r] = 1.f / l_run[r];
    u16* od = osw + (size_t)b * TB;
#pragma unroll
    for (int ch = 0; ch < 6; ++ch) {
#pragma unroll
        for (int cc = 0; cc < 4; ++cc)
#pragma unroll
            for (int r = 0; r < 4; ++r)
                pw[(quad * 4 + r) * 76 + cc * 16 + l15] = f2bf(Oa[ch * 4 + cc][r] * rl[r]);
#pragma unroll
        for (int ktl = 0; ktl < 2; ++ktl) {
            uint4_ vv = *(const uint4_*)(pw + l15 * 76 + ktl * 32 + quad * 8);
            size_t dst = ((size_t)rt * KT12 + ch * 2 + ktl) * 512 + (size_t)lane * 8;
            *(uint4_*)(od + dst) = vv;
        }
    }
}

extern "C" void kernel_launch(void* const* d_in, const int* in_sizes, int n_in,
                              void* d_out, int out_size, void* d_ws, size_t ws_size,
                              hipStream_t stream) {
    const float* rgb = (const float*)d_in[0];
    const float* ms  = (const float*)d_in[1];
    const float* Wq  = (const float*)d_in[2];
    const float* bq  = (const float*)d_in[3];
    const float* Wk  = (const float*)d_in[4];
    const float* bk  = (const float*)d_in[5];
    const float* Wv  = (const float*)d_in[6];
    const float* bv  = (const float*)d_in[7];
    const float* Wf  = (const float*)d_in[8];
    const float* bf_ = (const float*)d_in[9];
    float* outp = (float*)d_out;

    const float SC2 = 0.05103103630798288f * 1.4426950408889634f;  // scale*log2e

    const size_t TN = (size_t)BATCH * NTOK * DIMC;  // 12.58M elems
    const size_t WN = (size_t)DIMC * DIMC;          // 147456
    u16* rgb_sw = (u16*)d_ws;         // swizzle R=n K=c
    u16* ms_sw  = rgb_sw + TN;
    u16* q_sw   = ms_sw + TN;         // R=n K=d (pre-scaled)
    u16* k_sw   = q_sw + TN;          // R=m K=d
    u16* v_sw   = k_sw + TN;          // R=c K=m (KT=32)
    u16* o_sw   = v_sw + TN;          // R=n K=c
    u16* w_sw   = o_sw + TN;          // Wq,Wk,Wv,Wf swizzled concat
    // total ws: 6*25.2MB + 1.2MB = 152 MB

    wcvt_sw<<<dim3(72, 4), 256, 0, stream>>>(Wq, Wk, Wv, Wf, w_sw, SC2);
    transpose_sw<<<dim3(16, 6, 2 * BATCH), 256, 0, stream>>>(rgb, rgb_sw, ms, ms_sw);

    proj3_g<<<dim3(2304), 256, 0, stream>>>(
        rgb_sw, ms_sw, w_sw, q_sw, k_sw, v_sw, bq, bk, bv, SC2);

    attn_lds<<<dim3(256), 512, 0, stream>>>(q_sw, k_sw, v_sw, o_sw);

    projf_g<<<dim3(768), 256, 0, stream>>>(w_sw + 3 * WN, o_sw, bf_, outp);
}